// Round 5
// baseline (57169.147 us; speedup 1.0000x reference)
//
#include <hip/hip_runtime.h>
#include <hip/hip_bf16.h>

typedef __attribute__((ext_vector_type(8))) short bf16x8;
typedef __attribute__((ext_vector_type(4))) float f32x4;
typedef unsigned long long ull;

#define NB 512      // batch
#define NT 128      // timesteps
#define NC 66       // input channels
#define NH 512      // hidden
#define NW 10       // window
#define CP 96      // padded C (3 k-stages of 32)
#define BM 32       // batch tile
#define BJ 64       // j (h-dim) tile
#define NWG 256
#define NTHR 256
#define G3 1536     // 3*NH
#define NKS_H 16    // NH/32 k-stages
#define NKS_X 3     // CP/32 k-stages
#define FRAGN (NB * NH)   // u32 elems per frag buffer (1MB)

struct Params {
  const float *x, *Wih0, *Whh0, *bih0, *bhh0, *Wih1, *Whh1, *bih1, *bhh1, *tw, *tb, *sw, *sb;
  float *out;
  unsigned *barL, *barG;             // one-time global init barrier
  unsigned *cbar;                    // per-cluster (16x) phase barrier counters, 64B stride
  __hip_bfloat16 *Wih0h, *Wih0l;     // layer0 input weights, swizzled split, nks=3
  __hip_bfloat16 *Wch, *Wcl;         // composed Wc = Wih0 @ sw, swizzled split, nks=16
  __hip_bfloat16 *Whh0H, *Whh0L;     // swizzled split, nks=16
  __hip_bfloat16 *Wih1H, *Wih1L;
  __hip_bfloat16 *Whh1H, *Whh1L;
  float *cb;                         // cb = Wih0 @ sb  [G3]
  float *h0, *h1, *tvec;
  unsigned *h0f, *h1f, *tvf;         // packed split-bf16 A-fragment buffers
  __hip_bfloat16 *winb;              // sliding window, bf16, WG-private tiles
};

__device__ __forceinline__ float sigmoidf_(float x) { return 1.f / (1.f + __expf(-x)); }
__device__ __forceinline__ float tanhf_(float x) {
  float e = __expf(2.f * x);
  return (e - 1.f) / (e + 1.f);
}
__device__ __forceinline__ void split2(float v, __hip_bfloat16& h, __hip_bfloat16& l) {
  h = __float2bfloat16(v);
  l = __float2bfloat16(v - __bfloat162float(h));
}
__device__ __forceinline__ unsigned short bfbits(__hip_bfloat16 h) { return *(unsigned short*)&h; }
__device__ __forceinline__ void splitpack4(float4 v, ushort4& ph, ushort4& pl) {
  __hip_bfloat16 h, l;
  split2(v.x, h, l); ph.x = bfbits(h); pl.x = bfbits(l);
  split2(v.y, h, l); ph.y = bfbits(h); pl.y = bfbits(l);
  split2(v.z, h, l); ph.z = bfbits(h); pl.z = bfbits(l);
  split2(v.w, h, l); ph.w = bfbits(h); pl.w = bfbits(l);
}
// packed split-bf16: lo16 = hi-part, hi16 = lo-part
__device__ __forceinline__ unsigned packbf(float v) {
  __hip_bfloat16 h, l; split2(v, h, l);
  return (unsigned)bfbits(h) | ((unsigned)bfbits(l) << 16);
}

// device-coherent (cache-bypass) loads for cross-WG activation data
__device__ __forceinline__ float4 cload4(const float* p) {
  ull a = __hip_atomic_load((const ull*)p,       __ATOMIC_RELAXED, __HIP_MEMORY_SCOPE_AGENT);
  ull b = __hip_atomic_load(((const ull*)p) + 1, __ATOMIC_RELAXED, __HIP_MEMORY_SCOPE_AGENT);
  float4 r;
  ((ull*)&r)[0] = a;
  ((ull*)&r)[1] = b;
  return r;
}

// One-time global barrier after init: RELEASE -> L2 writeback so plain-stored
// init data (weights, zeroed frag bufs) is chip-visible. Poll: barG reaches 8.
__device__ __forceinline__ void gbar_init(unsigned* barL, unsigned* barG, int tid, int grp) {
  asm volatile("s_waitcnt vmcnt(0)" ::: "memory");
  __syncthreads();
  if (tid == 0) {
    unsigned old = __hip_atomic_fetch_add(&barL[grp * 32], 1u, __ATOMIC_RELEASE,
                                          __HIP_MEMORY_SCOPE_AGENT);
    if (old == 31u)
      __hip_atomic_fetch_add(barG, 1u, __ATOMIC_RELAXED, __HIP_MEMORY_SCOPE_AGENT);
    while (__hip_atomic_load(barG, __ATOMIC_RELAXED, __HIP_MEMORY_SCOPE_AGENT) < 8u)
      __builtin_amdgcn_s_sleep(2);
  }
  __syncthreads();
  asm volatile("" ::: "memory");
}

// 16-WG cluster barrier (logical IDs only -- placement-independent).
// All cross-WG data moves via agent-scope (cache-bypass) ops, so no cache
// maintenance needed; vmcnt(0) drains this WG's bypass stores to the
// coherence point before arrival. Counter zeroed by workspace memset.
__device__ __forceinline__ void xbar(unsigned* cnt, unsigned& ph, int tid) {
  asm volatile("s_waitcnt vmcnt(0)" ::: "memory");
  __syncthreads();
  ++ph;
  if (tid == 0) {
    __hip_atomic_fetch_add(cnt, 1u, __ATOMIC_RELAXED, __HIP_MEMORY_SCOPE_AGENT);
    while (__hip_atomic_load(cnt, __ATOMIC_RELAXED, __HIP_MEMORY_SCOPE_AGENT) < ph * 16u)
      __builtin_amdgcn_s_sleep(1);
  }
  __syncthreads();
  asm volatile("" ::: "memory");
}

__device__ __forceinline__ void zacc(f32x4 acc[2][4]) {
#pragma unroll
  for (int i = 0; i < 2; ++i)
#pragma unroll
    for (int g = 0; g < 4; ++g) {
      acc[i][g][0] = 0.f; acc[i][g][1] = 0.f; acc[i][g][2] = 0.f; acc[i][g][3] = 0.f;
    }
}

// Bulk A-tile loader: 64KB contiguous (2 b-blocks x 16 ks x 512 u32) from the
// frag buffer into LDS. Pipelined 4 groups of 8x8B agent-scope loads per
// thread (<=16 in flight, 32 data VGPRs) + linear ds_writes.
__device__ __forceinline__ void bulk_a(unsigned* __restrict__ alds,
                                       const unsigned* __restrict__ frag,
                                       int bb0, int tid) {
  const ull* g = (const ull*)(frag + (size_t)bb0 * 8192);
  ull* d = (ull*)alds;
  ull va[8], vb[8];
  auto ld8 = [&](ull (&a)[8], int grp) {
#pragma unroll
    for (int i = 0; i < 8; ++i)
      a[i] = __hip_atomic_load(g + (grp * 8 + i) * 256 + tid,
                               __ATOMIC_RELAXED, __HIP_MEMORY_SCOPE_AGENT);
  };
  auto st8 = [&](ull (&a)[8], int grp) {
#pragma unroll
    for (int i = 0; i < 8; ++i) d[(grp * 8 + i) * 256 + tid] = a[i];
  };
  ld8(va, 0); ld8(vb, 1);
  st8(va, 0); ld8(va, 2);
  st8(vb, 1); ld8(vb, 3);
  st8(va, 2); st8(vb, 3);
}

// (BM x 3*BJ) gate tile, nks=16: A from LDS frag tile (swizzled, conflict-free
// ds_read_b128 + cheap unpack), B register-direct from pre-swizzled global
// split-bf16 weights (plain cached loads), depth-2 pipeline.
template <int G2>
__device__ __forceinline__ void gemm_lds(
    f32x4 acc[2][4],
    const __hip_bfloat16* __restrict__ WH, const __hip_bfloat16* __restrict__ WL,
    const unsigned* __restrict__ aT, int j0, int tid)
{
  const int wv = tid >> 6, lane = tid & 63;
  const int ms = wv & 1, jh = wv >> 1;

  unsigned boff[6];
#pragma unroll
  for (int c = 0; c < 3; ++c)
#pragma unroll
    for (int jl = 0; jl < 2; ++jl) {
      const int jb = c * 32 + (j0 >> 4) + jh * 2 + jl;
      boff[c * 2 + jl] = (unsigned)((jb * NKS_H) * 64 + lane) * 8u;
    }
  const unsigned* ab = aT + ms * 8192;
  const unsigned i0 = ((unsigned)(lane * 8)) ^ ((unsigned)(lane & 7) << 2);

  uint4 bh0[6], bl0[6], bh1[6], bl1[6];
  auto loadB = [&](uint4 (&bh)[6], uint4 (&bl)[6], int st) {
    const unsigned so = (unsigned)st * 512u;
#pragma unroll
    for (int f = 0; f < 6; ++f) {
      bh[f] = *(const uint4*)(WH + boff[f] + so);
      bl[f] = *(const uint4*)(WL + boff[f] + so);
    }
  };
  auto readA = [&](bf16x8& ah, bf16x8& al, int st) {
    const unsigned* ap = ab + st * 512;
    const uint4 ua = *(const uint4*)(ap + i0);          // elems e0..3
    const uint4 ub = *(const uint4*)(ap + (i0 ^ 4u));   // elems e4..7
    uint4 uh, ul;
    uh.x = (ua.x & 0xffffu) | (ua.y << 16);  ul.x = (ua.x >> 16) | (ua.y & 0xffff0000u);
    uh.y = (ua.z & 0xffffu) | (ua.w << 16);  ul.y = (ua.z >> 16) | (ua.w & 0xffff0000u);
    uh.z = (ub.x & 0xffffu) | (ub.y << 16);  ul.z = (ub.x >> 16) | (ub.y & 0xffff0000u);
    uh.w = (ub.z & 0xffffu) | (ub.w << 16);  ul.w = (ub.z >> 16) | (ub.w & 0xffff0000u);
    ah = *(const bf16x8*)&uh;
    al = *(const bf16x8*)&ul;
  };
  auto comp = [&](const uint4 (&bh)[6], const uint4 (&bl)[6], bf16x8 ah, bf16x8 al) {
#pragma unroll
    for (int jl = 0; jl < 2; ++jl)
#pragma unroll
      for (int c = 0; c < 3; ++c) {
        const int f = c * 2 + jl;
        const int g = (c == 2) ? G2 : c;
        const bf16x8 vbh = *(const bf16x8*)&bh[f];
        const bf16x8 vbl = *(const bf16x8*)&bl[f];
        acc[jl][g] = __builtin_amdgcn_mfma_f32_16x16x32_bf16(ah, vbh, acc[jl][g], 0, 0, 0);
        acc[jl][g] = __builtin_amdgcn_mfma_f32_16x16x32_bf16(al, vbh, acc[jl][g], 0, 0, 0);
        acc[jl][g] = __builtin_amdgcn_mfma_f32_16x16x32_bf16(ah, vbl, acc[jl][g], 0, 0, 0);
      }
  };

  bf16x8 a0h, a0l, a1h, a1l;
  loadB(bh0, bl0, 0); loadB(bh1, bl1, 1);
  readA(a0h, a0l, 0); readA(a1h, a1l, 1);
  for (int st = 0; st < NKS_H; st += 2) {
    comp(bh0, bl0, a0h, a0l);
    if (st + 2 < NKS_H) { loadB(bh0, bl0, st + 2); readA(a0h, a0l, st + 2); }
    comp(bh1, bl1, a1h, a1l);
    if (st + 3 < NKS_H) { loadB(bh1, bl1, st + 3); readA(a1h, a1l, st + 3); }
  }
}

// x-input gate tile (nks=3): x is an immutable input -> plain cached loads.
template <int G2>
__device__ __forceinline__ void gemm_x(
    f32x4 acc[2][4],
    const __hip_bfloat16* __restrict__ WH, const __hip_bfloat16* __restrict__ WL,
    const float* __restrict__ X, int tstep, int b0, int j0, int tid)
{
  const int wv = tid >> 6, lane = tid & 63, quad = lane >> 4, l15 = lane & 15;
  const int ms = wv & 1, jh = wv >> 1;
  const int arow = b0 + ms * 16 + l15;

  unsigned boff[6];
#pragma unroll
  for (int c = 0; c < 3; ++c)
#pragma unroll
    for (int jl = 0; jl < 2; ++jl) {
      const int jb = c * 32 + (j0 >> 4) + jh * 2 + jl;
      boff[c * 2 + jl] = (unsigned)((jb * NKS_X) * 64 + lane) * 8u;
    }
  const float* arp = X + ((size_t)arow * NT + tstep) * NC;

  float a[3][8];
#pragma unroll
  for (int st = 0; st < 3; ++st) {
    const int k0 = st * 32 + (quad << 3);
#pragma unroll
    for (int e = 0; e < 8; ++e) a[st][e] = (k0 + e < NC) ? arp[k0 + e] : 0.f;
  }

  uint4 bh0[6], bl0[6], bh1[6], bl1[6];
  auto loadB = [&](uint4 (&bh)[6], uint4 (&bl)[6], int st) {
    const unsigned so = (unsigned)st * 512u;
#pragma unroll
    for (int f = 0; f < 6; ++f) {
      bh[f] = *(const uint4*)(WH + boff[f] + so);
      bl[f] = *(const uint4*)(WL + boff[f] + so);
    }
  };
  auto comp = [&](const uint4 (&bh)[6], const uint4 (&bl)[6], const float (&av)[8]) {
    float4 v0, v1;
    v0.x = av[0]; v0.y = av[1]; v0.z = av[2]; v0.w = av[3];
    v1.x = av[4]; v1.y = av[5]; v1.z = av[6]; v1.w = av[7];
    ushort4 ph0, pl0, ph1, pl1;
    splitpack4(v0, ph0, pl0);
    splitpack4(v1, ph1, pl1);
    bf16x8 ah, al;
    ((ushort4*)&ah)[0] = ph0; ((ushort4*)&ah)[1] = ph1;
    ((ushort4*)&al)[0] = pl0; ((ushort4*)&al)[1] = pl1;
#pragma unroll
    for (int jl = 0; jl < 2; ++jl)
#pragma unroll
      for (int c = 0; c < 3; ++c) {
        const int f = c * 2 + jl;
        const int g = (c == 2) ? G2 : c;
        const bf16x8 vbh = *(const bf16x8*)&bh[f];
        const bf16x8 vbl = *(const bf16x8*)&bl[f];
        acc[jl][g] = __builtin_amdgcn_mfma_f32_16x16x32_bf16(ah, vbh, acc[jl][g], 0, 0, 0);
        acc[jl][g] = __builtin_amdgcn_mfma_f32_16x16x32_bf16(al, vbh, acc[jl][g], 0, 0, 0);
        acc[jl][g] = __builtin_amdgcn_mfma_f32_16x16x32_bf16(ah, vbl, acc[jl][g], 0, 0, 0);
      }
  };

  loadB(bh0, bl0, 0); loadB(bh1, bl1, 1);
  comp(bh0, bl0, a[0]);
  loadB(bh0, bl0, 2);
  comp(bh1, bl1, a[1]);
  comp(bh0, bl0, a[2]);
}

// GRU elementwise. fp32 h / window: WG-private plain ops. Cross-WG frag:
// staged in LDS (frag-linear) then a contiguous agent-scope store sweep.
__device__ __forceinline__ void ew_gru(
    f32x4 acc[2][4],
    const float* __restrict__ bi, const float* __restrict__ bh,
    const float* __restrict__ hold, float* __restrict__ hnew,
    unsigned* __restrict__ hfrag,
    int b0, int j0, int tid, __hip_bfloat16* win, int slot,
    unsigned* __restrict__ stg)
{
  const int wv = tid >> 6, lane = tid & 63, quad = lane >> 4, l15 = lane & 15;
  const int ms = wv & 1, jh = wv >> 1;
  const int bb0 = b0 >> 4, jcb = j0 >> 5;
  __syncthreads();   // staging buffer may still be read by lagging gemm threads
#pragma unroll
  for (int jlf = 0; jlf < 2; ++jlf) {
    const int j = j0 + jh * 32 + jlf * 16 + l15;
    const float br = bi[j] + bh[j];
    const float bz = bi[NH + j] + bh[NH + j];
    const float bni = bi[2 * NH + j];
    const float bnh = bh[2 * NH + j];
#pragma unroll
    for (int rg = 0; rg < 4; ++rg) {
      const int b = b0 + ms * 16 + quad * 4 + rg;
      const float r = sigmoidf_(acc[jlf][0][rg] + br);
      const float z = sigmoidf_(acc[jlf][1][rg] + bz);
      const float n = tanhf_(acc[jlf][2][rg] + bni + r * (acc[jlf][3][rg] + bnh));
      const float h = hold[(size_t)b * NH + j];
      const float hn = (1.f - z) * n + z * h;
      hnew[(size_t)b * NH + j] = hn;
      const int lanep = (quad * 4 + rg) | ((jlf * 2 + (l15 >> 3)) << 4);
      const int s = (lanep * 8 + (l15 & 7)) ^ ((lanep & 7) << 2);
      stg[ms * 1024 + jh * 512 + s] = packbf(hn);
      if (win) win[((size_t)b * NW + slot) * NH + j] = __float2bfloat16(hn);
    }
  }
  __syncthreads();
#pragma unroll
  for (int i = 0; i < 4; ++i) {
    const int q = i * 256 + tid;
    const int chunk = q >> 9, rem = q & 511;
    ull* gb = (ull*)hfrag + ((size_t)(bb0 + chunk) * 16 + jcb) * 256;
    __hip_atomic_store(gb + rem, ((const ull*)stg)[q],
                       __ATOMIC_RELAXED, __HIP_MEMORY_SCOPE_AGENT);
  }
}

// decoder layer-1 EW: h1 fp32/window private; h1f + tvf frags via LDS-staged
// bypass sweep; tvec fp32 via agent-scope stores (read by frame_out).
__device__ __forceinline__ void ew_dec1(
    f32x4 acc[2][4], const Params& P, float* __restrict__ h1p,
    int b0, int j0, int tid, int s, unsigned* __restrict__ stg)
{
  const int wv = tid >> 6, lane = tid & 63, quad = lane >> 4, l15 = lane & 15;
  const int ms = wv & 1, jh = wv >> 1;
  const int bb0 = b0 >> 4, jcb = j0 >> 5;
  const int slot = s % NW;
  float twv[NW];
#pragma unroll
  for (int k = 0; k < NW; ++k) {
    int idx = k - slot - 1; if (idx < 0) idx += NW;
    twv[k] = P.tw[idx];
  }
  const float tw9 = P.tw[NW - 1];
  const float tb0 = P.tb[0];
  __syncthreads();
#pragma unroll
  for (int jlf = 0; jlf < 2; ++jlf) {
    const int j = j0 + jh * 32 + jlf * 16 + l15;
    const float br = P.bih1[j] + P.bhh1[j];
    const float bz = P.bih1[NH + j] + P.bhh1[NH + j];
    const float bni = P.bih1[2 * NH + j];
    const float bnh = P.bhh1[2 * NH + j];
#pragma unroll
    for (int rg = 0; rg < 4; ++rg) {
      const int b = b0 + ms * 16 + quad * 4 + rg;
      const float r = sigmoidf_(acc[jlf][0][rg] + br);
      const float z = sigmoidf_(acc[jlf][1][rg] + bz);
      const float n = tanhf_(acc[jlf][2][rg] + bni + r * (acc[jlf][3][rg] + bnh));
      const float h = h1p[(size_t)b * NH + j];
      const float hn = (1.f - z) * n + z * h;
      h1p[(size_t)b * NH + j] = hn;
      __hip_bfloat16* wrow = P.winb + (size_t)b * NW * NH + j;
      wrow[(size_t)slot * NH] = __float2bfloat16(hn);
      float ts = tb0 + hn * tw9;
#pragma unroll
      for (int k = 0; k < NW; ++k) {
        if (k == slot) continue;
        ts += __bfloat162float(wrow[(size_t)k * NH]) * twv[k];
      }
      __hip_atomic_store(&P.tvec[(size_t)b * NH + j], ts,
                         __ATOMIC_RELAXED, __HIP_MEMORY_SCOPE_AGENT);
      const int lanep = (quad * 4 + rg) | ((jlf * 2 + (l15 >> 3)) << 4);
      const int sw = (lanep * 8 + (l15 & 7)) ^ ((lanep & 7) << 2);
      stg[ms * 1024 + jh * 512 + sw] = packbf(hn);
      stg[2048 + ms * 1024 + jh * 512 + sw] = packbf(ts);
    }
  }
  __syncthreads();
#pragma unroll
  for (int i = 0; i < 8; ++i) {
    const int q2 = i * 256 + tid;
    const int buf = q2 >> 10, q = q2 & 1023;
    const int chunk = q >> 9, rem = q & 511;
    unsigned* base = buf ? P.tvf : (P.h1f + FRAGN);
    ull* gb = (ull*)base + ((size_t)(bb0 + chunk) * 16 + jcb) * 256;
    __hip_atomic_store(gb + rem, ((const ull*)stg)[q2],
                       __ATOMIC_RELAXED, __HIP_MEMORY_SCOPE_AGENT);
  }
}

__global__ __launch_bounds__(NTHR) void rnn_kernel(Params P) {
  __shared__ __align__(16) unsigned aT0[16384];   // 64KB A-tile 0 (+ ew staging)
  __shared__ __align__(16) unsigned aT1[16384];   // 64KB A-tile 1
  __shared__ __align__(16) float tl[4 * NH];      // 8KB frame staging
  const int tid = threadIdx.x;
  const int wg = blockIdx.x;
  const int grp = wg & 7;
  const size_t gid = (size_t)wg * NTHR + tid;
  const size_t GT = (size_t)NWG * NTHR;
  const int wv = tid >> 6, lane = tid & 63, l15 = lane & 15;
  const int jh = wv >> 1;

  // ---- logical roles (no placement assumptions) ----
  const bool isL1 = wg >= 128;
  const int tile = wg & 127;
  const int b0 = (tile >> 3) * BM;
  const int j0 = (tile & 7) * BJ;
  const int bb0 = b0 >> 4;
  const int jidx = tile & 7;
  const int cluster = tile >> 3;                 // 16 independent b-block clusters
  unsigned* ccnt = P.cbar + (size_t)cluster * 16;

  // ---- init: build swizzled split-bf16 weights (plain stores; flushed to L3
  // by the single RELEASE barrier below) ----
  for (size_t f = gid; f < (size_t)G3 * CP / 8; f += GT) {
    const int ln = (int)(f & 63), blk = (int)(f >> 6);
    const int ks = blk % NKS_X, jb = blk / NKS_X;
    const int r = jb * 16 + (ln & 15);
    const int k0 = ks * 32 + ((ln >> 4) << 3);
#pragma unroll
    for (int e = 0; e < 8; ++e) {
      const int k = k0 + e;
      split2(k < NC ? P.Wih0[(size_t)r * NC + k] : 0.f,
             P.Wih0h[f * 8 + e], P.Wih0l[f * 8 + e]);
    }
  }
  {
    const float* srcs[3] = { P.Whh0, P.Wih1, P.Whh1 };
    __hip_bfloat16* dhs[3] = { P.Whh0H, P.Wih1H, P.Whh1H };
    __hip_bfloat16* dls[3] = { P.Whh0L, P.Wih1L, P.Whh1L };
#pragma unroll
    for (int m = 0; m < 3; ++m) {
      const float* __restrict__ W = srcs[m];
      __hip_bfloat16* __restrict__ DH = dhs[m];
      __hip_bfloat16* __restrict__ DL = dls[m];
      for (size_t f = gid; f < (size_t)G3 * NH / 8; f += GT) {
        const int ln = (int)(f & 63), blk = (int)(f >> 6);
        const int ks = blk & 15, jb = blk >> 4;
        const int r = jb * 16 + (ln & 15);
        const int k0 = ks * 32 + ((ln >> 4) << 3);
        const float* src = W + (size_t)r * NH + k0;
        ushort4 h0v, l0v, h1v, l1v;
        splitpack4(*(const float4*)(src), h0v, l0v);
        splitpack4(*(const float4*)(src + 4), h1v, l1v);
        *(ushort4*)(DH + f * 8)     = h0v;
        *(ushort4*)(DH + f * 8 + 4) = h1v;
        *(ushort4*)(DL + f * 8)     = l0v;
        *(ushort4*)(DL + f * 8 + 4) = l1v;
      }
    }
  }
  for (size_t f = gid; f < (size_t)G3 * NH / 8; f += GT) {
    const int ln = (int)(f & 63), blk = (int)(f >> 6);
    const int ks = blk & 15, jb = blk >> 4;
    const int r = jb * 16 + (ln & 15);
    const int k0 = ks * 32 + ((ln >> 4) << 3);
    float s[8] = {0.f, 0.f, 0.f, 0.f, 0.f, 0.f, 0.f, 0.f};
    for (int c = 0; c < NC; ++c) {
      const float a = P.Wih0[(size_t)r * NC + c];
      const float4 w0 = *(const float4*)(P.sw + (size_t)c * NH + k0);
      const float4 w1 = *(const float4*)(P.sw + (size_t)c * NH + k0 + 4);
      s[0] += a * w0.x; s[1] += a * w0.y; s[2] += a * w0.z; s[3] += a * w0.w;
      s[4] += a * w1.x; s[5] += a * w1.y; s[6] += a * w1.z; s[7] += a * w1.w;
    }
#pragma unroll
    for (int e = 0; e < 8; ++e) split2(s[e], P.Wch[f * 8 + e], P.Wcl[f * 8 + e]);
  }
  for (size_t i = gid; i < (size_t)G3; i += GT) {
    float a = 0.f;
    for (int c = 0; c < NC; ++c) a += P.Wih0[i * NC + c] * P.sb[c];
    P.cb[i] = a;
  }
  // ---- role-based zeroing: exactly the state each WG's cluster consumes ----
  if (!isL1) {
    for (int i = tid; i < BM * BJ; i += NTHR) {
      const int b = b0 + (i >> 6), j = j0 + (i & 63);
      P.h0[(size_t)b * NH + j] = 0.f;                 // h0 fp32 buf0 (t=0 hold)
    }
    unsigned* z = P.h0f + (size_t)bb0 * 8192 + (size_t)jidx * 2048;
    for (int i = tid; i < 2048; i += NTHR) z[i] = 0u; // h0f buf0 (t=0 A-tile)
  } else {
    for (int i = tid; i < BM * BJ; i += NTHR) {
      const int b = b0 + (i >> 6), j = j0 + (i & 63);
      P.h1[(size_t)NB * NH + (size_t)b * NH + j] = 0.f;  // h1 fp32 buf1 (t=1 hold)
    }
    unsigned* z = P.h1f + (size_t)FRAGN + (size_t)bb0 * 8192 + (size_t)jidx * 2048;
    for (int i = tid; i < 2048; i += NTHR) z[i] = 0u;    // h1f buf1 (t=1 A-tile)
  }
  gbar_init(P.barL, P.barG, tid, grp);   // one-time global release barrier

  unsigned ph = 0;
  float G[2][3][4];

  // ---- encoder: pipelined L0/L1, one cluster barrier per iteration ----
  for (int t = 0; t <= NT; ++t) {
    const int cur = t & 1;
    float* h0c = P.h0 + (size_t)cur * NB * NH;
    float* h0n = P.h0 + (size_t)(cur ^ 1) * NB * NH;
    float* h1c = P.h1 + (size_t)cur * NB * NH;
    float* h1n = P.h1 + (size_t)(cur ^ 1) * NB * NH;
    f32x4 acc[2][4];
    if (!isL1) {
      if (t < NT) {
        zacc(acc);
        bulk_a(aT0, P.h0f + (size_t)cur * FRAGN, bb0, tid);
        gemm_x<2>(acc, P.Wih0h, P.Wih0l, P.x, t, b0, j0, tid);
        __syncthreads();
        gemm_lds<3>(acc, P.Whh0H, P.Whh0L, aT0, j0, tid);
        ew_gru(acc, P.bih0, P.bhh0, h0c, h0n, P.h0f + (size_t)(cur ^ 1) * FRAGN,
               b0, j0, tid, nullptr, 0, aT0);
      } else {
        zacc(acc);
        gemm_x<2>(acc, P.Wih0h, P.Wih0l, P.x, NT - 1, b0, j0, tid);
#pragma unroll
        for (int jlf = 0; jlf < 2; ++jlf)
#pragma unroll
          for (int c = 0; c < 3; ++c)
#pragma unroll
            for (int rg = 0; rg < 4; ++rg) G[jlf][c][rg] = acc[jlf][c][rg];
      }
    } else {
      if (t >= 1) {
        zacc(acc);
        bulk_a(aT0, P.h0f + (size_t)cur * FRAGN, bb0, tid);
        bulk_a(aT1, P.h1f + (size_t)cur * FRAGN, bb0, tid);
        __syncthreads();
        gemm_lds<2>(acc, P.Wih1H, P.Wih1L, aT0, j0, tid);
        gemm_lds<3>(acc, P.Whh1H, P.Whh1L, aT1, j0, tid);
        ew_gru(acc, P.bih1, P.bhh1, h1c, h1n, P.h1f + (size_t)(cur ^ 1) * FRAGN,
               b0, j0, tid, (t >= 119) ? P.winb : nullptr, t - 119, aT0);
      }
    }
    xbar(ccnt, ph, tid);
  }

  int d0 = 0;
  float* h1p = P.h1 + (size_t)NB * NH;

  float cbr[2][3];
  float Freg[2];
  const int frow = wg * 4;   // L0 frame rows (within own cluster's b-block)
  if (!isL1) {
#pragma unroll
    for (int jlf = 0; jlf < 2; ++jlf)
#pragma unroll
      for (int c = 0; c < 3; ++c)
        cbr[jlf][c] = P.cb[c * NH + j0 + jh * 32 + jlf * 16 + l15];
#pragma unroll
    for (int v = 0; v < 2; ++v) {
      const int t2 = tid + v * NTHR;
      if (t2 < 4 * NC) {
        const int bl = t2 / NC, c = t2 - bl * NC, b = frow + bl;
        Freg[v] = P.x[((size_t)b * NT + (NT - 1)) * NC + c];
      }
    }
  }

  auto frame_out = [&](int sout) {   // F += tvec_sout @ sw^T + sb; write out rows frow..+3
    const float* tvb = P.tvec + (size_t)frow * NH;
    *(float4*)&tl[tid * 8] = cload4(tvb + tid * 8);
    *(float4*)&tl[tid * 8 + 4] = cload4(tvb + tid * 8 + 4);
    __syncthreads();
#pragma unroll
    for (int v = 0; v < 2; ++v) {
      const int t2 = tid + v * NTHR;
      if (t2 < 4 * NC) {
        const int bl = t2 / NC, c = t2 - bl * NC, b = frow + bl;
        float f = Freg[v] + P.sb[c];
        const float4* swr = (const float4*)(P.sw + (size_t)c * NH);
        const float4* tr = (const float4*)(tl + bl * NH);
#pragma unroll 8
        for (int h4 = 0; h4 < NH / 4; ++h4) {
          float4 tv = tr[h4], wv4 = swr[h4];
          f += tv.x * wv4.x + tv.y * wv4.y + tv.z * wv4.z + tv.w * wv4.w;
        }
        Freg[v] = f;
        P.out[((size_t)b * NT + sout) * NC + c] = f;
      }
    }
    __syncthreads();
  };

  // ---- decoder: 2 cluster barriers per step ----
  for (int s = 0; s < NT; ++s) {
    float* h0c = P.h0 + (size_t)d0 * NB * NH;
    float* h0n = P.h0 + (size_t)(d0 ^ 1) * NB * NH;
    f32x4 acc[2][4];
    if (!isL1) {
      if (s >= 1) frame_out(s - 1);
      zacc(acc);
      bulk_a(aT1, P.h0f + (size_t)d0 * FRAGN, bb0, tid);
      if (s >= 1) bulk_a(aT0, P.tvf, bb0, tid);
      __syncthreads();
      if (s >= 1)
        gemm_lds<2>(acc, P.Wch, P.Wcl, aT0, j0, tid);
#pragma unroll
      for (int jlf = 0; jlf < 2; ++jlf)
#pragma unroll
        for (int c = 0; c < 3; ++c)
#pragma unroll
          for (int rg = 0; rg < 4; ++rg) {
            float g = G[jlf][c][rg] + acc[jlf][c][rg] + (s >= 1 ? cbr[jlf][c] : 0.f);
            G[jlf][c][rg] = g;
            acc[jlf][c][rg] = g;
          }
      gemm_lds<3>(acc, P.Whh0H, P.Whh0L, aT1, j0, tid);
      ew_gru(acc, P.bih0, P.bhh0, h0c, h0n, P.h0f + (size_t)(d0 ^ 1) * FRAGN,
             b0, j0, tid, nullptr, 0, aT0);
    } else {
      zacc(acc);
      bulk_a(aT0, P.h1f + (size_t)FRAGN, bb0, tid);
      __syncthreads();
      gemm_lds<3>(acc, P.Whh1H, P.Whh1L, aT0, j0, tid);
    }
    xbar(ccnt, ph, tid);
    if (isL1) {
      bulk_a(aT1, P.h0f + (size_t)(d0 ^ 1) * FRAGN, bb0, tid);
      __syncthreads();
      gemm_lds<2>(acc, P.Wih1H, P.Wih1L, aT1, j0, tid);
      ew_dec1(acc, P, h1p, b0, j0, tid, s, aT0);
    }
    xbar(ccnt, ph, tid);
    d0 ^= 1;
  }
  if (!isL1) frame_out(NT - 1);
}

extern "C" void kernel_launch(void* const* d_in, const int* in_sizes, int n_in,
                              void* d_out, int out_size, void* d_ws, size_t ws_size,
                              hipStream_t stream) {
  (void)in_sizes; (void)n_in; (void)out_size; (void)ws_size;
  Params P;
  P.x    = (const float*)d_in[0];
  P.Wih0 = (const float*)d_in[1];
  P.Whh0 = (const float*)d_in[2];
  P.bih0 = (const float*)d_in[3];
  P.bhh0 = (const float*)d_in[4];
  P.Wih1 = (const float*)d_in[5];
  P.Whh1 = (const float*)d_in[6];
  P.bih1 = (const float*)d_in[7];
  P.bhh1 = (const float*)d_in[8];
  P.tw   = (const float*)d_in[9];
  P.tb   = (const float*)d_in[10];
  P.sw   = (const float*)d_in[11];
  P.sb   = (const float*)d_in[12];
  P.out  = (float*)d_out;

  char* w = (char*)d_ws;
  size_t used = 0;
  auto take = [&](size_t bytes) {
    char* p = w + used;
    used += (bytes + 255) & ~(size_t)255;
    return p;
  };
  unsigned* bar = (unsigned*)take(4096);
  P.barL  = bar;            // 8 groups * 32-stride u32 = 1024B
  P.barG  = bar + 256;
  P.cbar  = bar + 320;      // 16 clusters * 16 u32 (64B stride)
  P.Wih0h = (__hip_bfloat16*)take((size_t)G3 * CP * 2);
  P.Wih0l = (__hip_bfloat16*)take((size_t)G3 * CP * 2);
  P.Wch   = (__hip_bfloat16*)take((size_t)G3 * NH * 2);
  P.Wcl   = (__hip_bfloat16*)take((size_t)G3 * NH * 2);
  P.Whh0H = (__hip_bfloat16*)take((size_t)G3 * NH * 2);
  P.Whh0L = (__hip_bfloat16*)take((size_t)G3 * NH * 2);
  P.Wih1H = (__hip_bfloat16*)take((size_t)G3 * NH * 2);
  P.Wih1L = (__hip_bfloat16*)take((size_t)G3 * NH * 2);
  P.Whh1H = (__hip_bfloat16*)take((size_t)G3 * NH * 2);
  P.Whh1L = (__hip_bfloat16*)take((size_t)G3 * NH * 2);
  P.cb    = (float*)take((size_t)G3 * 4);
  P.h0    = (float*)take((size_t)2 * NB * NH * 4);
  P.h1    = (float*)take((size_t)2 * NB * NH * 4);
  P.tvec  = (float*)take((size_t)NB * NH * 4);
  P.h0f   = (unsigned*)take((size_t)2 * FRAGN * 4);
  P.h1f   = (unsigned*)take((size_t)2 * FRAGN * 4);
  P.tvf   = (unsigned*)take((size_t)FRAGN * 4);
  P.winb  = (__hip_bfloat16*)take((size_t)NB * NW * NH * 2);

  hipMemsetAsync(d_ws, 0, 4096, stream);
  rnn_kernel<<<dim3(NWG), dim3(NTHR), 0, stream>>>(P);
}

// Round 6
// 45374.847 us; speedup vs baseline: 1.2599x; 1.2599x over previous
//
#include <hip/hip_runtime.h>
#include <hip/hip_bf16.h>

typedef __attribute__((ext_vector_type(8))) short bf16x8;
typedef __attribute__((ext_vector_type(4))) float f32x4;
typedef unsigned long long ull;

#define NB 512      // batch
#define NT 128      // timesteps
#define NC 66       // input channels
#define NH 512      // hidden
#define NW 10       // window
#define CP 96       // padded C (3 k-stages of 32)
#define BM 32       // batch tile
#define BJ 64       // j (h-dim) tile
#define NWG 256
#define NTHR 256
#define G3 1536     // 3*NH
#define NKS_H 16    // NH/32 k-stages
#define NKS_X 3     // CP/32 k-stages
#define FRAGN (NB * NH)   // u32 elems per frag buffer (1MB)

struct Params {
  const float *x, *Wih0, *Whh0, *bih0, *bhh0, *Wih1, *Whh1, *bih1, *bhh1, *tw, *tb, *sw, *sb;
  float *out;
  unsigned *barL, *barG;             // one-time global init barrier
  unsigned *cbar;                    // per-cluster (16x) phase barrier counters, 64B stride
  __hip_bfloat16 *Wih0h, *Wih0l;     // layer0 input weights, swizzled split, nks=3
  __hip_bfloat16 *Wch, *Wcl;         // composed Wc = Wih0 @ sw, swizzled split, nks=16
  __hip_bfloat16 *Whh0H, *Whh0L;     // swizzled split, nks=16
  __hip_bfloat16 *Wih1H, *Wih1L;
  __hip_bfloat16 *Whh1H, *Whh1L;
  float *cb;                         // cb = Wih0 @ sb  [G3]
  float *tvec;
  unsigned *h0f, *h1f, *tvf;         // packed split-bf16 A-fragment buffers
};

__device__ __forceinline__ float sigmoidf_(float x) { return 1.f / (1.f + __expf(-x)); }
__device__ __forceinline__ float tanhf_(float x) {
  float e = __expf(2.f * x);
  return (e - 1.f) / (e + 1.f);
}
__device__ __forceinline__ void split2(float v, __hip_bfloat16& h, __hip_bfloat16& l) {
  h = __float2bfloat16(v);
  l = __float2bfloat16(v - __bfloat162float(h));
}
__device__ __forceinline__ unsigned short bfbits(__hip_bfloat16 h) { return *(unsigned short*)&h; }
__device__ __forceinline__ void splitpack4(float4 v, ushort4& ph, ushort4& pl) {
  __hip_bfloat16 h, l;
  split2(v.x, h, l); ph.x = bfbits(h); pl.x = bfbits(l);
  split2(v.y, h, l); ph.y = bfbits(h); pl.y = bfbits(l);
  split2(v.z, h, l); ph.z = bfbits(h); pl.z = bfbits(l);
  split2(v.w, h, l); ph.w = bfbits(h); pl.w = bfbits(l);
}
// packed split-bf16: lo16 = hi-part, hi16 = lo-part
__device__ __forceinline__ unsigned packbf(float v) {
  __hip_bfloat16 h, l; split2(v, h, l);
  return (unsigned)bfbits(h) | ((unsigned)bfbits(l) << 16);
}
__device__ __forceinline__ unsigned short f2bfb(float v) {
  __hip_bfloat16 h = __float2bfloat16(v);
  return bfbits(h);
}
__device__ __forceinline__ float bfb2f(unsigned short u) {
  __hip_bfloat16 h = *(__hip_bfloat16*)&u;
  return __bfloat162float(h);
}

// device-coherent (cache-bypass) loads for cross-WG activation data
__device__ __forceinline__ float4 cload4(const float* p) {
  ull a = __hip_atomic_load((const ull*)p,       __ATOMIC_RELAXED, __HIP_MEMORY_SCOPE_AGENT);
  ull b = __hip_atomic_load(((const ull*)p) + 1, __ATOMIC_RELAXED, __HIP_MEMORY_SCOPE_AGENT);
  float4 r;
  ((ull*)&r)[0] = a;
  ((ull*)&r)[1] = b;
  return r;
}

// One-time global barrier after init: RELEASE -> L2 writeback so plain-stored
// init data (weights) is chip-visible. Poll: barG reaches 8.
__device__ __forceinline__ void gbar_init(unsigned* barL, unsigned* barG, int tid, int grp) {
  asm volatile("s_waitcnt vmcnt(0)" ::: "memory");
  __syncthreads();
  if (tid == 0) {
    unsigned old = __hip_atomic_fetch_add(&barL[grp * 32], 1u, __ATOMIC_RELEASE,
                                          __HIP_MEMORY_SCOPE_AGENT);
    if (old == 31u)
      __hip_atomic_fetch_add(barG, 1u, __ATOMIC_RELAXED, __HIP_MEMORY_SCOPE_AGENT);
    while (__hip_atomic_load(barG, __ATOMIC_RELAXED, __HIP_MEMORY_SCOPE_AGENT) < 8u)
      __builtin_amdgcn_s_sleep(2);
  }
  __syncthreads();
  asm volatile("" ::: "memory");
}

// 16-WG cluster barrier (logical IDs only). All cross-WG data moves via
// agent-scope ops; vmcnt(0) drains them before arrival.
__device__ __forceinline__ void xbar(unsigned* cnt, unsigned& ph, int tid) {
  asm volatile("s_waitcnt vmcnt(0)" ::: "memory");
  __syncthreads();
  ++ph;
  if (tid == 0) {
    __hip_atomic_fetch_add(cnt, 1u, __ATOMIC_RELAXED, __HIP_MEMORY_SCOPE_AGENT);
    while (__hip_atomic_load(cnt, __ATOMIC_RELAXED, __HIP_MEMORY_SCOPE_AGENT) < ph * 16u)
      __builtin_amdgcn_s_sleep(1);
  }
  __syncthreads();
  asm volatile("" ::: "memory");
}

__device__ __forceinline__ void zacc(f32x4 acc[2][4]) {
#pragma unroll
  for (int i = 0; i < 2; ++i)
#pragma unroll
    for (int g = 0; g < 4; ++g) {
      acc[i][g][0] = 0.f; acc[i][g][1] = 0.f; acc[i][g][2] = 0.f; acc[i][g][3] = 0.f;
    }
}

// Bulk A-tile loader: 64KB contiguous from the frag buffer into LDS.
// Pipelined 4 groups of 8x8B agent-scope loads per thread.
__device__ __forceinline__ void bulk_a(unsigned* __restrict__ alds,
                                       const unsigned* __restrict__ frag,
                                       int bb0, int tid) {
  const ull* g = (const ull*)(frag + (size_t)bb0 * 8192);
  ull* d = (ull*)alds;
  ull va[8], vb[8];
  auto ld8 = [&](ull (&a)[8], int grp) {
#pragma unroll
    for (int i = 0; i < 8; ++i)
      a[i] = __hip_atomic_load(g + (grp * 8 + i) * 256 + tid,
                               __ATOMIC_RELAXED, __HIP_MEMORY_SCOPE_AGENT);
  };
  auto st8 = [&](ull (&a)[8], int grp) {
#pragma unroll
    for (int i = 0; i < 8; ++i) d[(grp * 8 + i) * 256 + tid] = a[i];
  };
  ld8(va, 0); ld8(vb, 1);
  st8(va, 0); ld8(va, 2);
  st8(vb, 1); ld8(vb, 3);
  st8(va, 2); st8(vb, 3);
}

// (BM x 3*BJ) gate tile, nks=16: A from LDS frag tile, B register-direct from
// pre-swizzled global split-bf16 weights (plain cached loads -> L2-resident).
template <int G2>
__device__ __forceinline__ void gemm_lds(
    f32x4 acc[2][4],
    const __hip_bfloat16* __restrict__ WH, const __hip_bfloat16* __restrict__ WL,
    const unsigned* __restrict__ aT, int j0, int tid)
{
  const int wv = tid >> 6, lane = tid & 63;
  const int ms = wv & 1, jh = wv >> 1;

  unsigned boff[6];
#pragma unroll
  for (int c = 0; c < 3; ++c)
#pragma unroll
    for (int jl = 0; jl < 2; ++jl) {
      const int jb = c * 32 + (j0 >> 4) + jh * 2 + jl;
      boff[c * 2 + jl] = (unsigned)((jb * NKS_H) * 64 + lane) * 8u;
    }
  const unsigned* ab = aT + ms * 8192;
  const unsigned i0 = ((unsigned)(lane * 8)) ^ ((unsigned)(lane & 7) << 2);

  uint4 bh0[6], bl0[6], bh1[6], bl1[6];
  auto loadB = [&](uint4 (&bh)[6], uint4 (&bl)[6], int st) {
    const unsigned so = (unsigned)st * 512u;
#pragma unroll
    for (int f = 0; f < 6; ++f) {
      bh[f] = *(const uint4*)(WH + boff[f] + so);
      bl[f] = *(const uint4*)(WL + boff[f] + so);
    }
  };
  auto readA = [&](bf16x8& ah, bf16x8& al, int st) {
    const unsigned* ap = ab + st * 512;
    const uint4 ua = *(const uint4*)(ap + i0);          // elems e0..3
    const uint4 ub = *(const uint4*)(ap + (i0 ^ 4u));   // elems e4..7
    uint4 uh, ul;
    uh.x = (ua.x & 0xffffu) | (ua.y << 16);  ul.x = (ua.x >> 16) | (ua.y & 0xffff0000u);
    uh.y = (ua.z & 0xffffu) | (ua.w << 16);  ul.y = (ua.z >> 16) | (ua.w & 0xffff0000u);
    uh.z = (ub.x & 0xffffu) | (ub.y << 16);  ul.z = (ub.x >> 16) | (ub.y & 0xffff0000u);
    uh.w = (ub.z & 0xffffu) | (ub.w << 16);  ul.w = (ub.z >> 16) | (ub.w & 0xffff0000u);
    ah = *(const bf16x8*)&uh;
    al = *(const bf16x8*)&ul;
  };
  auto comp = [&](const uint4 (&bh)[6], const uint4 (&bl)[6], bf16x8 ah, bf16x8 al) {
#pragma unroll
    for (int jl = 0; jl < 2; ++jl)
#pragma unroll
      for (int c = 0; c < 3; ++c) {
        const int f = c * 2 + jl;
        const int g = (c == 2) ? G2 : c;
        const bf16x8 vbh = *(const bf16x8*)&bh[f];
        const bf16x8 vbl = *(const bf16x8*)&bl[f];
        acc[jl][g] = __builtin_amdgcn_mfma_f32_16x16x32_bf16(ah, vbh, acc[jl][g], 0, 0, 0);
        acc[jl][g] = __builtin_amdgcn_mfma_f32_16x16x32_bf16(al, vbh, acc[jl][g], 0, 0, 0);
        acc[jl][g] = __builtin_amdgcn_mfma_f32_16x16x32_bf16(ah, vbl, acc[jl][g], 0, 0, 0);
      }
  };

  bf16x8 a0h, a0l, a1h, a1l;
  loadB(bh0, bl0, 0); loadB(bh1, bl1, 1);
  readA(a0h, a0l, 0); readA(a1h, a1l, 1);
  for (int st = 0; st < NKS_H; st += 2) {
    comp(bh0, bl0, a0h, a0l);
    if (st + 2 < NKS_H) { loadB(bh0, bl0, st + 2); readA(a0h, a0l, st + 2); }
    comp(bh1, bl1, a1h, a1l);
    if (st + 3 < NKS_H) { loadB(bh1, bl1, st + 3); readA(a1h, a1l, st + 3); }
  }
}

// x-input gate tile (nks=3): x is an immutable input -> plain cached loads.
template <int G2>
__device__ __forceinline__ void gemm_x(
    f32x4 acc[2][4],
    const __hip_bfloat16* __restrict__ WH, const __hip_bfloat16* __restrict__ WL,
    const float* __restrict__ X, int tstep, int b0, int j0, int tid)
{
  const int wv = tid >> 6, lane = tid & 63, quad = lane >> 4, l15 = lane & 15;
  const int ms = wv & 1, jh = wv >> 1;
  const int arow = b0 + ms * 16 + l15;

  unsigned boff[6];
#pragma unroll
  for (int c = 0; c < 3; ++c)
#pragma unroll
    for (int jl = 0; jl < 2; ++jl) {
      const int jb = c * 32 + (j0 >> 4) + jh * 2 + jl;
      boff[c * 2 + jl] = (unsigned)((jb * NKS_X) * 64 + lane) * 8u;
    }
  const float* arp = X + ((size_t)arow * NT + tstep) * NC;

  float a[3][8];
#pragma unroll
  for (int st = 0; st < 3; ++st) {
    const int k0 = st * 32 + (quad << 3);
#pragma unroll
    for (int e = 0; e < 8; ++e) a[st][e] = (k0 + e < NC) ? arp[k0 + e] : 0.f;
  }

  uint4 bh0[6], bl0[6], bh1[6], bl1[6];
  auto loadB = [&](uint4 (&bh)[6], uint4 (&bl)[6], int st) {
    const unsigned so = (unsigned)st * 512u;
#pragma unroll
    for (int f = 0; f < 6; ++f) {
      bh[f] = *(const uint4*)(WH + boff[f] + so);
      bl[f] = *(const uint4*)(WL + boff[f] + so);
    }
  };
  auto comp = [&](const uint4 (&bh)[6], const uint4 (&bl)[6], const float (&av)[8]) {
    float4 v0, v1;
    v0.x = av[0]; v0.y = av[1]; v0.z = av[2]; v0.w = av[3];
    v1.x = av[4]; v1.y = av[5]; v1.z = av[6]; v1.w = av[7];
    ushort4 ph0, pl0, ph1, pl1;
    splitpack4(v0, ph0, pl0);
    splitpack4(v1, ph1, pl1);
    bf16x8 ah, al;
    ((ushort4*)&ah)[0] = ph0; ((ushort4*)&ah)[1] = ph1;
    ((ushort4*)&al)[0] = pl0; ((ushort4*)&al)[1] = pl1;
#pragma unroll
    for (int jl = 0; jl < 2; ++jl)
#pragma unroll
      for (int c = 0; c < 3; ++c) {
        const int f = c * 2 + jl;
        const int g = (c == 2) ? G2 : c;
        const bf16x8 vbh = *(const bf16x8*)&bh[f];
        const bf16x8 vbl = *(const bf16x8*)&bl[f];
        acc[jl][g] = __builtin_amdgcn_mfma_f32_16x16x32_bf16(ah, vbh, acc[jl][g], 0, 0, 0);
        acc[jl][g] = __builtin_amdgcn_mfma_f32_16x16x32_bf16(al, vbh, acc[jl][g], 0, 0, 0);
        acc[jl][g] = __builtin_amdgcn_mfma_f32_16x16x32_bf16(ah, vbl, acc[jl][g], 0, 0, 0);
      }
  };

  loadB(bh0, bl0, 0); loadB(bh1, bl1, 1);
  comp(bh0, bl0, a[0]);
  loadB(bh0, bl0, 2);
  comp(bh1, bl1, a[1]);
  comp(bh0, bl0, a[2]);
}

// GRU elementwise. h-hold carried in REGISTERS (thread-private across steps).
// Window (if any) lives in LDS (WG-private ring). Cross-WG frag: staged in LDS
// then contiguous agent-scope store sweep (no L2 pollution).
__device__ __forceinline__ void ew_gru(
    f32x4 acc[2][4],
    const float* __restrict__ bi, const float* __restrict__ bh,
    float (&hreg)[2][4],
    unsigned* __restrict__ hfrag,
    int b0, int j0, int tid, ushort* winl, int slot,
    unsigned* __restrict__ stg)
{
  const int wv = tid >> 6, lane = tid & 63, quad = lane >> 4, l15 = lane & 15;
  const int ms = wv & 1, jh = wv >> 1;
  const int bb0 = b0 >> 4, jcb = j0 >> 5;
  __syncthreads();   // staging buffer may still be read by lagging gemm threads
#pragma unroll
  for (int jlf = 0; jlf < 2; ++jlf) {
    const int j = j0 + jh * 32 + jlf * 16 + l15;
    const float br = bi[j] + bh[j];
    const float bz = bi[NH + j] + bh[NH + j];
    const float bni = bi[2 * NH + j];
    const float bnh = bh[2 * NH + j];
#pragma unroll
    for (int rg = 0; rg < 4; ++rg) {
      const float r = sigmoidf_(acc[jlf][0][rg] + br);
      const float z = sigmoidf_(acc[jlf][1][rg] + bz);
      const float n = tanhf_(acc[jlf][2][rg] + bni + r * (acc[jlf][3][rg] + bnh));
      const float h = hreg[jlf][rg];
      const float hn = (1.f - z) * n + z * h;
      hreg[jlf][rg] = hn;
      const int lanep = (quad * 4 + rg) | ((jlf * 2 + (l15 >> 3)) << 4);
      const int s = (lanep * 8 + (l15 & 7)) ^ ((lanep & 7) << 2);
      stg[ms * 1024 + jh * 512 + s] = packbf(hn);
      if (winl) winl[slot * 2048 + (jlf * 4 + rg) * 256 + tid] = f2bfb(hn);
    }
  }
  __syncthreads();
#pragma unroll
  for (int i = 0; i < 4; ++i) {
    const int q = i * 256 + tid;
    const int chunk = q >> 9, rem = q & 511;
    ull* gb = (ull*)hfrag + ((size_t)(bb0 + chunk) * 16 + jcb) * 256;
    __hip_atomic_store(gb + rem, ((const ull*)stg)[q],
                       __ATOMIC_RELAXED, __HIP_MEMORY_SCOPE_AGENT);
  }
}

// decoder layer-1 EW: h1 hold in registers; window ring in LDS; h1f + tvf
// frags via LDS-staged agent sweep; tvec fp32 via agent stores.
__device__ __forceinline__ void ew_dec1(
    f32x4 acc[2][4], const Params& P, float (&hreg)[2][4],
    int b0, int j0, int tid, int s, unsigned* __restrict__ stg, ushort* winl)
{
  const int wv = tid >> 6, lane = tid & 63, quad = lane >> 4, l15 = lane & 15;
  const int ms = wv & 1, jh = wv >> 1;
  const int bb0 = b0 >> 4, jcb = j0 >> 5;
  const int slot = s % NW;
  float twv[NW];
#pragma unroll
  for (int k = 0; k < NW; ++k) {
    int idx = k - slot - 1; if (idx < 0) idx += NW;
    twv[k] = P.tw[idx];
  }
  const float tw9 = P.tw[NW - 1];
  const float tb0 = P.tb[0];
  __syncthreads();
#pragma unroll
  for (int jlf = 0; jlf < 2; ++jlf) {
    const int j = j0 + jh * 32 + jlf * 16 + l15;
    const float br = P.bih1[j] + P.bhh1[j];
    const float bz = P.bih1[NH + j] + P.bhh1[NH + j];
    const float bni = P.bih1[2 * NH + j];
    const float bnh = P.bhh1[2 * NH + j];
#pragma unroll
    for (int rg = 0; rg < 4; ++rg) {
      const int b = b0 + ms * 16 + quad * 4 + rg;
      const float r = sigmoidf_(acc[jlf][0][rg] + br);
      const float z = sigmoidf_(acc[jlf][1][rg] + bz);
      const float n = tanhf_(acc[jlf][2][rg] + bni + r * (acc[jlf][3][rg] + bnh));
      const float h = hreg[jlf][rg];
      const float hn = (1.f - z) * n + z * h;
      hreg[jlf][rg] = hn;
      const int widx = (jlf * 4 + rg) * 256 + tid;
      winl[slot * 2048 + widx] = f2bfb(hn);
      float ts = tb0 + hn * tw9;
#pragma unroll
      for (int k = 0; k < NW; ++k) {
        if (k == slot) continue;
        ts += bfb2f(winl[k * 2048 + widx]) * twv[k];
      }
      __hip_atomic_store(&P.tvec[(size_t)b * NH + j], ts,
                         __ATOMIC_RELAXED, __HIP_MEMORY_SCOPE_AGENT);
      const int lanep = (quad * 4 + rg) | ((jlf * 2 + (l15 >> 3)) << 4);
      const int sw = (lanep * 8 + (l15 & 7)) ^ ((lanep & 7) << 2);
      stg[ms * 1024 + jh * 512 + sw] = packbf(hn);
      stg[2048 + ms * 1024 + jh * 512 + sw] = packbf(ts);
    }
  }
  __syncthreads();
#pragma unroll
  for (int i = 0; i < 8; ++i) {
    const int q2 = i * 256 + tid;
    const int buf = q2 >> 10, q = q2 & 1023;
    const int chunk = q >> 9, rem = q & 511;
    unsigned* base = buf ? P.tvf : (P.h1f + FRAGN);
    ull* gb = (ull*)base + ((size_t)(bb0 + chunk) * 16 + jcb) * 256;
    __hip_atomic_store(gb + rem, ((const ull*)stg)[q2],
                       __ATOMIC_RELAXED, __HIP_MEMORY_SCOPE_AGENT);
  }
}

__global__ __launch_bounds__(NTHR) void rnn_kernel(Params P) {
  __shared__ __align__(16) unsigned aT[16384];    // 64KB A-tile (+ ew staging)
  __shared__ __align__(16) ushort winl[20480];    // 40KB window ring (L1 WGs)
  __shared__ __align__(16) float tl[4 * NH];      // 8KB frame staging (L0 WGs)
  const int tid = threadIdx.x;
  const int wg = blockIdx.x;
  const int grp = wg & 7;
  const size_t gid = (size_t)wg * NTHR + tid;
  const size_t GT = (size_t)NWG * NTHR;
  const int wv = tid >> 6, lane = tid & 63, l15 = lane & 15;
  const int jh = wv >> 1;

  // ---- logical roles (no placement assumptions; j0 aligns with wg%8 so each
  // XCD's resident weight slice is ~1.7MB under round-robin dispatch) ----
  const bool isL1 = wg >= 128;
  const int tile = wg & 127;
  const int b0 = (tile >> 3) * BM;
  const int j0 = (tile & 7) * BJ;
  const int bb0 = b0 >> 4;
  const int jidx = tile & 7;
  const int cluster = tile >> 3;                 // 16 independent b-block clusters
  unsigned* ccnt = P.cbar + (size_t)cluster * 16;

  // ---- init: build swizzled split-bf16 weights (plain stores; flushed to L3
  // by the single RELEASE barrier below) ----
  for (size_t f = gid; f < (size_t)G3 * CP / 8; f += GT) {
    const int ln = (int)(f & 63), blk = (int)(f >> 6);
    const int ks = blk % NKS_X, jb = blk / NKS_X;
    const int r = jb * 16 + (ln & 15);
    const int k0 = ks * 32 + ((ln >> 4) << 3);
#pragma unroll
    for (int e = 0; e < 8; ++e) {
      const int k = k0 + e;
      split2(k < NC ? P.Wih0[(size_t)r * NC + k] : 0.f,
             P.Wih0h[f * 8 + e], P.Wih0l[f * 8 + e]);
    }
  }
  {
    const float* srcs[3] = { P.Whh0, P.Wih1, P.Whh1 };
    __hip_bfloat16* dhs[3] = { P.Whh0H, P.Wih1H, P.Whh1H };
    __hip_bfloat16* dls[3] = { P.Whh0L, P.Wih1L, P.Whh1L };
#pragma unroll
    for (int m = 0; m < 3; ++m) {
      const float* __restrict__ W = srcs[m];
      __hip_bfloat16* __restrict__ DH = dhs[m];
      __hip_bfloat16* __restrict__ DL = dls[m];
      for (size_t f = gid; f < (size_t)G3 * NH / 8; f += GT) {
        const int ln = (int)(f & 63), blk = (int)(f >> 6);
        const int ks = blk & 15, jb = blk >> 4;
        const int r = jb * 16 + (ln & 15);
        const int k0 = ks * 32 + ((ln >> 4) << 3);
        const float* src = W + (size_t)r * NH + k0;
        ushort4 h0v, l0v, h1v, l1v;
        splitpack4(*(const float4*)(src), h0v, l0v);
        splitpack4(*(const float4*)(src + 4), h1v, l1v);
        *(ushort4*)(DH + f * 8)     = h0v;
        *(ushort4*)(DH + f * 8 + 4) = h1v;
        *(ushort4*)(DL + f * 8)     = l0v;
        *(ushort4*)(DL + f * 8 + 4) = l1v;
      }
    }
  }
  for (size_t f = gid; f < (size_t)G3 * NH / 8; f += GT) {
    const int ln = (int)(f & 63), blk = (int)(f >> 6);
    const int ks = blk & 15, jb = blk >> 4;
    const int r = jb * 16 + (ln & 15);
    const int k0 = ks * 32 + ((ln >> 4) << 3);
    float s[8] = {0.f, 0.f, 0.f, 0.f, 0.f, 0.f, 0.f, 0.f};
    for (int c = 0; c < NC; ++c) {
      const float a = P.Wih0[(size_t)r * NC + c];
      const float4 w0 = *(const float4*)(P.sw + (size_t)c * NH + k0);
      const float4 w1 = *(const float4*)(P.sw + (size_t)c * NH + k0 + 4);
      s[0] += a * w0.x; s[1] += a * w0.y; s[2] += a * w0.z; s[3] += a * w0.w;
      s[4] += a * w1.x; s[5] += a * w1.y; s[6] += a * w1.z; s[7] += a * w1.w;
    }
#pragma unroll
    for (int e = 0; e < 8; ++e) split2(s[e], P.Wch[f * 8 + e], P.Wcl[f * 8 + e]);
  }
  for (size_t i = gid; i < (size_t)G3; i += GT) {
    float a = 0.f;
    for (int c = 0; c < NC; ++c) a += P.Wih0[i * NC + c] * P.sb[c];
    P.cb[i] = a;
  }
  // ---- role-based zeroing via agent stores (no dirty/stale L2 lines):
  // collectively covers h0f buf0 and h1f buf1 (first-consumed A-tiles) ----
  {
    unsigned* z = (!isL1 ? P.h0f : (P.h1f + FRAGN)) + (size_t)bb0 * 8192 + (size_t)jidx * 2048;
    for (int i = tid; i < 2048; i += NTHR)
      __hip_atomic_store(z + i, 0u, __ATOMIC_RELAXED, __HIP_MEMORY_SCOPE_AGENT);
  }
  gbar_init(P.barL, P.barG, tid, grp);   // one-time global release barrier

  unsigned ph = 0;
  float G[2][3][4];
  float hreg[2][4] = {{0.f, 0.f, 0.f, 0.f}, {0.f, 0.f, 0.f, 0.f}};  // h-hold (L0: h0, L1: h1)

  // ---- encoder: pipelined L0/L1, one cluster barrier per iteration ----
  for (int t = 0; t <= NT; ++t) {
    const int cur = t & 1;
    f32x4 acc[2][4];
    if (!isL1) {
      if (t < NT) {
        zacc(acc);
        bulk_a(aT, P.h0f + (size_t)cur * FRAGN, bb0, tid);
        gemm_x<2>(acc, P.Wih0h, P.Wih0l, P.x, t, b0, j0, tid);
        __syncthreads();
        gemm_lds<3>(acc, P.Whh0H, P.Whh0L, aT, j0, tid);
        ew_gru(acc, P.bih0, P.bhh0, hreg, P.h0f + (size_t)(cur ^ 1) * FRAGN,
               b0, j0, tid, nullptr, 0, aT);
      } else {
        zacc(acc);
        gemm_x<2>(acc, P.Wih0h, P.Wih0l, P.x, NT - 1, b0, j0, tid);
#pragma unroll
        for (int jlf = 0; jlf < 2; ++jlf)
#pragma unroll
          for (int c = 0; c < 3; ++c)
#pragma unroll
            for (int rg = 0; rg < 4; ++rg) G[jlf][c][rg] = acc[jlf][c][rg];
      }
    } else {
      if (t >= 1) {
        zacc(acc);
        bulk_a(aT, P.h0f + (size_t)cur * FRAGN, bb0, tid);
        __syncthreads();
        gemm_lds<2>(acc, P.Wih1H, P.Wih1L, aT, j0, tid);
        __syncthreads();
        bulk_a(aT, P.h1f + (size_t)cur * FRAGN, bb0, tid);
        __syncthreads();
        gemm_lds<3>(acc, P.Whh1H, P.Whh1L, aT, j0, tid);
        ew_gru(acc, P.bih1, P.bhh1, hreg, P.h1f + (size_t)(cur ^ 1) * FRAGN,
               b0, j0, tid, (t >= 119) ? winl : nullptr, t - 119, aT);
      }
    }
    xbar(ccnt, ph, tid);
  }

  int d0 = 0;

  float cbr[2][3];
  float Freg[2];
  const int frow = wg * 4;   // L0 frame rows (within own cluster's b-block)
  if (!isL1) {
#pragma unroll
    for (int jlf = 0; jlf < 2; ++jlf)
#pragma unroll
      for (int c = 0; c < 3; ++c)
        cbr[jlf][c] = P.cb[c * NH + j0 + jh * 32 + jlf * 16 + l15];
#pragma unroll
    for (int v = 0; v < 2; ++v) {
      const int t2 = tid + v * NTHR;
      if (t2 < 4 * NC) {
        const int bl = t2 / NC, c = t2 - bl * NC, b = frow + bl;
        Freg[v] = P.x[((size_t)b * NT + (NT - 1)) * NC + c];
      }
    }
  }

  auto frame_out = [&](int sout) {   // F += tvec_sout @ sw^T + sb; write out rows frow..+3
    const float* tvb = P.tvec + (size_t)frow * NH;
    *(float4*)&tl[tid * 8] = cload4(tvb + tid * 8);
    *(float4*)&tl[tid * 8 + 4] = cload4(tvb + tid * 8 + 4);
    __syncthreads();
#pragma unroll
    for (int v = 0; v < 2; ++v) {
      const int t2 = tid + v * NTHR;
      if (t2 < 4 * NC) {
        const int bl = t2 / NC, c = t2 - bl * NC, b = frow + bl;
        float f = Freg[v] + P.sb[c];
        const float4* swr = (const float4*)(P.sw + (size_t)c * NH);
        const float4* tr = (const float4*)(tl + bl * NH);
#pragma unroll 8
        for (int h4 = 0; h4 < NH / 4; ++h4) {
          float4 tv = tr[h4], wv4 = swr[h4];
          f += tv.x * wv4.x + tv.y * wv4.y + tv.z * wv4.z + tv.w * wv4.w;
        }
        Freg[v] = f;
        __builtin_nontemporal_store(f, &P.out[((size_t)b * NT + sout) * NC + c]);
      }
    }
    __syncthreads();
  };

  // ---- decoder: 2 cluster barriers per step ----
  for (int s = 0; s < NT; ++s) {
    f32x4 acc[2][4];
    if (!isL1) {
      zacc(acc);
      if (s >= 1) {
        frame_out(s - 1);
        bulk_a(aT, P.tvf, bb0, tid);
        __syncthreads();
        gemm_lds<2>(acc, P.Wch, P.Wcl, aT, j0, tid);
        __syncthreads();
      }
      bulk_a(aT, P.h0f + (size_t)d0 * FRAGN, bb0, tid);
      __syncthreads();
#pragma unroll
      for (int jlf = 0; jlf < 2; ++jlf)
#pragma unroll
        for (int c = 0; c < 3; ++c)
#pragma unroll
          for (int rg = 0; rg < 4; ++rg) {
            float g = G[jlf][c][rg] + acc[jlf][c][rg] + (s >= 1 ? cbr[jlf][c] : 0.f);
            G[jlf][c][rg] = g;
            acc[jlf][c][rg] = g;
          }
      gemm_lds<3>(acc, P.Whh0H, P.Whh0L, aT, j0, tid);
      ew_gru(acc, P.bih0, P.bhh0, hreg, P.h0f + (size_t)(d0 ^ 1) * FRAGN,
             b0, j0, tid, nullptr, 0, aT);
    } else {
      zacc(acc);
      bulk_a(aT, P.h1f + (size_t)FRAGN, bb0, tid);
      __syncthreads();
      gemm_lds<3>(acc, P.Whh1H, P.Whh1L, aT, j0, tid);
      __syncthreads();
    }
    xbar(ccnt, ph, tid);
    if (isL1) {
      bulk_a(aT, P.h0f + (size_t)(d0 ^ 1) * FRAGN, bb0, tid);
      __syncthreads();
      gemm_lds<2>(acc, P.Wih1H, P.Wih1L, aT, j0, tid);
      ew_dec1(acc, P, hreg, b0, j0, tid, s, aT, winl);
    }
    xbar(ccnt, ph, tid);
    d0 ^= 1;
  }
  if (!isL1) frame_out(NT - 1);
}

extern "C" void kernel_launch(void* const* d_in, const int* in_sizes, int n_in,
                              void* d_out, int out_size, void* d_ws, size_t ws_size,
                              hipStream_t stream) {
  (void)in_sizes; (void)n_in; (void)out_size; (void)ws_size;
  Params P;
  P.x    = (const float*)d_in[0];
  P.Wih0 = (const float*)d_in[1];
  P.Whh0 = (const float*)d_in[2];
  P.bih0 = (const float*)d_in[3];
  P.bhh0 = (const float*)d_in[4];
  P.Wih1 = (const float*)d_in[5];
  P.Whh1 = (const float*)d_in[6];
  P.bih1 = (const float*)d_in[7];
  P.bhh1 = (const float*)d_in[8];
  P.tw   = (const float*)d_in[9];
  P.tb   = (const float*)d_in[10];
  P.sw   = (const float*)d_in[11];
  P.sb   = (const float*)d_in[12];
  P.out  = (float*)d_out;

  char* w = (char*)d_ws;
  size_t used = 0;
  auto take = [&](size_t bytes) {
    char* p = w + used;
    used += (bytes + 255) & ~(size_t)255;
    return p;
  };
  unsigned* bar = (unsigned*)take(4096);
  P.barL  = bar;            // 8 groups * 32-stride u32 = 1024B
  P.barG  = bar + 256;
  P.cbar  = bar + 320;      // 16 clusters * 16 u32 (64B stride)
  P.Wih0h = (__hip_bfloat16*)take((size_t)G3 * CP * 2);
  P.Wih0l = (__hip_bfloat16*)take((size_t)G3 * CP * 2);
  P.Wch   = (__hip_bfloat16*)take((size_t)G3 * NH * 2);
  P.Wcl   = (__hip_bfloat16*)take((size_t)G3 * NH * 2);
  P.Whh0H = (__hip_bfloat16*)take((size_t)G3 * NH * 2);
  P.Whh0L = (__hip_bfloat16*)take((size_t)G3 * NH * 2);
  P.Wih1H = (__hip_bfloat16*)take((size_t)G3 * NH * 2);
  P.Wih1L = (__hip_bfloat16*)take((size_t)G3 * NH * 2);
  P.Whh1H = (__hip_bfloat16*)take((size_t)G3 * NH * 2);
  P.Whh1L = (__hip_bfloat16*)take((size_t)G3 * NH * 2);
  P.cb    = (float*)take((size_t)G3 * 4);
  P.tvec  = (float*)take((size_t)NB * NH * 4);
  P.h0f   = (unsigned*)take((size_t)2 * FRAGN * 4);
  P.h1f   = (unsigned*)take((size_t)2 * FRAGN * 4);
  P.tvf   = (unsigned*)take((size_t)FRAGN * 4);

  hipMemsetAsync(d_ws, 0, 4096, stream);
  rnn_kernel<<<dim3(NWG), dim3(NTHR), 0, stream>>>(P);
}

// Round 7
// 16520.810 us; speedup vs baseline: 3.4604x; 2.7465x over previous
//
#include <hip/hip_runtime.h>
#include <hip/hip_bf16.h>

typedef __attribute__((ext_vector_type(8))) short bf16x8;
typedef __attribute__((ext_vector_type(4))) float f32x4;
typedef unsigned long long ull;

#define NB 512      // batch
#define NT 128      // timesteps
#define NC 66       // input channels
#define NH 512      // hidden
#define NW 10       // window
#define CP 96       // padded C (3 k-stages of 32)
#define BM 32       // batch tile
#define BJ 64       // j (h-dim) tile
#define NWG 256
#define NTHR 256
#define G3 1536     // 3*NH
#define NKS_H 16    // NH/32 k-stages
#define NKS_X 3     // CP/32 k-stages
#define FRAGN (NB * NH)   // u32 elems per frag buffer (1MB)

struct Params {
  const float *x, *Wih0, *Whh0, *bih0, *bhh0, *Wih1, *Whh1, *bih1, *bhh1, *tw, *tb, *sw, *sb;
  float *out;
  unsigned *barL, *barG;             // one-time global init barrier
  unsigned *cbar;                    // per-cluster (16x) phase barrier counters, 64B stride
  __hip_bfloat16 *Wih0h, *Wih0l;     // layer0 input weights, swizzled split, nks=3
  __hip_bfloat16 *Wch, *Wcl;         // composed Wc = Wih0 @ sw, swizzled split, nks=16
  __hip_bfloat16 *Whh0H, *Whh0L;     // swizzled split, nks=16
  __hip_bfloat16 *Wih1H, *Wih1L;
  __hip_bfloat16 *Whh1H, *Whh1L;
  float *cb;                         // cb = Wih0 @ sb  [G3]
  float *tvec;
  unsigned *h0f, *h1f, *tvf;         // packed split-bf16 A-fragment buffers
};

__device__ __forceinline__ float sigmoidf_(float x) { return 1.f / (1.f + __expf(-x)); }
__device__ __forceinline__ float tanhf_(float x) {
  float e = __expf(2.f * x);
  return (e - 1.f) / (e + 1.f);
}
__device__ __forceinline__ void split2(float v, __hip_bfloat16& h, __hip_bfloat16& l) {
  h = __float2bfloat16(v);
  l = __float2bfloat16(v - __bfloat162float(h));
}
__device__ __forceinline__ unsigned short bfbits(__hip_bfloat16 h) { return *(unsigned short*)&h; }
__device__ __forceinline__ void splitpack4(float4 v, ushort4& ph, ushort4& pl) {
  __hip_bfloat16 h, l;
  split2(v.x, h, l); ph.x = bfbits(h); pl.x = bfbits(l);
  split2(v.y, h, l); ph.y = bfbits(h); pl.y = bfbits(l);
  split2(v.z, h, l); ph.z = bfbits(h); pl.z = bfbits(l);
  split2(v.w, h, l); ph.w = bfbits(h); pl.w = bfbits(l);
}
// packed split-bf16: lo16 = hi-part, hi16 = lo-part
__device__ __forceinline__ unsigned packbf(float v) {
  __hip_bfloat16 h, l; split2(v, h, l);
  return (unsigned)bfbits(h) | ((unsigned)bfbits(l) << 16);
}
__device__ __forceinline__ unsigned short f2bfb(float v) {
  __hip_bfloat16 h = __float2bfloat16(v);
  return bfbits(h);
}
__device__ __forceinline__ float bfb2f(unsigned short u) {
  __hip_bfloat16 h = *(__hip_bfloat16*)&u;
  return __bfloat162float(h);
}

// async global->LDS, 16B/lane; LDS dest = wave-uniform base + lane*16
__device__ __forceinline__ void gld_lds16(const void* g, void* l) {
  __builtin_amdgcn_global_load_lds(
      (const __attribute__((address_space(1))) unsigned*)g,
      (__attribute__((address_space(3))) unsigned*)l, 16, 0, 0);
}

// device-coherent (cache-bypass) loads for cross-WG activation data
__device__ __forceinline__ float4 cload4(const float* p) {
  ull a = __hip_atomic_load((const ull*)p,       __ATOMIC_RELAXED, __HIP_MEMORY_SCOPE_AGENT);
  ull b = __hip_atomic_load(((const ull*)p) + 1, __ATOMIC_RELAXED, __HIP_MEMORY_SCOPE_AGENT);
  float4 r;
  ((ull*)&r)[0] = a;
  ((ull*)&r)[1] = b;
  return r;
}

// One-time global barrier after init: RELEASE -> L2 writeback so plain-stored
// init data (weights) is chip-visible. Poll: barG reaches 8.
__device__ __forceinline__ void gbar_init(unsigned* barL, unsigned* barG, int tid, int grp) {
  asm volatile("s_waitcnt vmcnt(0)" ::: "memory");
  __syncthreads();
  if (tid == 0) {
    unsigned old = __hip_atomic_fetch_add(&barL[grp * 32], 1u, __ATOMIC_RELEASE,
                                          __HIP_MEMORY_SCOPE_AGENT);
    if (old == 31u)
      __hip_atomic_fetch_add(barG, 1u, __ATOMIC_RELAXED, __HIP_MEMORY_SCOPE_AGENT);
    while (__hip_atomic_load(barG, __ATOMIC_RELAXED, __HIP_MEMORY_SCOPE_AGENT) < 8u)
      __builtin_amdgcn_s_sleep(2);
  }
  __syncthreads();
  asm volatile("" ::: "memory");
}

// 16-WG cluster barrier (logical IDs only). All cross-WG data moves via
// agent-scope ops; vmcnt(0) drains them before arrival.
__device__ __forceinline__ void xbar(unsigned* cnt, unsigned& ph, int tid) {
  asm volatile("s_waitcnt vmcnt(0)" ::: "memory");
  __syncthreads();
  ++ph;
  if (tid == 0) {
    __hip_atomic_fetch_add(cnt, 1u, __ATOMIC_RELAXED, __HIP_MEMORY_SCOPE_AGENT);
    while (__hip_atomic_load(cnt, __ATOMIC_RELAXED, __HIP_MEMORY_SCOPE_AGENT) < ph * 16u)
      __builtin_amdgcn_s_sleep(1);
  }
  __syncthreads();
  asm volatile("" ::: "memory");
}

__device__ __forceinline__ void zacc(f32x4 acc[2][4]) {
#pragma unroll
  for (int i = 0; i < 2; ++i)
#pragma unroll
    for (int g = 0; g < 4; ++g) {
      acc[i][g][0] = 0.f; acc[i][g][1] = 0.f; acc[i][g][2] = 0.f; acc[i][g][3] = 0.f;
    }
}

// Bulk A-tile loader: 64KB contiguous from the frag buffer into LDS.
// Pipelined 4 groups of 8x8B agent-scope loads per thread.
__device__ __forceinline__ void bulk_a(unsigned* __restrict__ alds,
                                       const unsigned* __restrict__ frag,
                                       int bb0, int tid) {
  const ull* g = (const ull*)(frag + (size_t)bb0 * 8192);
  ull* d = (ull*)alds;
  ull va[8], vb[8];
  auto ld8 = [&](ull (&a)[8], int grp) {
#pragma unroll
    for (int i = 0; i < 8; ++i)
      a[i] = __hip_atomic_load(g + (grp * 8 + i) * 256 + tid,
                               __ATOMIC_RELAXED, __HIP_MEMORY_SCOPE_AGENT);
  };
  auto st8 = [&](ull (&a)[8], int grp) {
#pragma unroll
    for (int i = 0; i < 8; ++i) d[(grp * 8 + i) * 256 + tid] = a[i];
  };
  ld8(va, 0); ld8(vb, 1);
  st8(va, 0); ld8(va, 2);
  st8(vb, 1); ld8(vb, 3);
  st8(va, 2); st8(vb, 3);
}

// (BM x 3*BJ) gate tile, nks=16: A from LDS frag tile; B staged via ASYNC
// global_load_lds into a double-buffered LDS slot (counted vmcnt, zero data
// VGPRs -> deep in-flight pipeline). Two s_barriers/stage bound wave skew so
// slot reuse cannot race. Math order identical to prior rounds.
template <int G2>
__device__ __forceinline__ void gemm_lds(
    f32x4 acc[2][4],
    const __hip_bfloat16* __restrict__ WH, const __hip_bfloat16* __restrict__ WL,
    const unsigned* __restrict__ aT, unsigned* __restrict__ Bst, int j0, int tid)
{
  const int wv = tid >> 6, lane = tid & 63;
  const int ms = wv & 1, jh = wv >> 1;

  const __hip_bfloat16* wsrc[12];
#pragma unroll
  for (int c = 0; c < 3; ++c)
#pragma unroll
    for (int jl = 0; jl < 2; ++jl) {
      const int jb = c * 32 + (j0 >> 4) + jh * 2 + jl;
      const unsigned bo = (unsigned)((jb * NKS_H) * 64 + lane) * 8u;
      wsrc[(c * 2 + jl) * 2 + 0] = WH + bo;
      wsrc[(c * 2 + jl) * 2 + 1] = WL + bo;
    }
  unsigned* const bb = Bst + jh * 6144;            // [jh][slot2][chunk12][256 u32]
  const unsigned* ab = aT + ms * 8192;
  const unsigned i0 = ((unsigned)(lane * 8)) ^ ((unsigned)(lane & 7) << 2);
  const int lofs = lane * 4;

  auto issueB = [&](int st) {
    unsigned* sb = bb + (st & 1) * 3072;
#pragma unroll
    for (int k = 0; k < 12; ++k)
      gld_lds16(wsrc[k] + (size_t)st * 512, sb + k * 256);
  };
  auto readA = [&](bf16x8& ah, bf16x8& al, int st) {
    const unsigned* ap = ab + st * 512;
    const uint4 ua = *(const uint4*)(ap + i0);          // elems e0..3
    const uint4 ub = *(const uint4*)(ap + (i0 ^ 4u));   // elems e4..7
    uint4 uh, ul;
    uh.x = (ua.x & 0xffffu) | (ua.y << 16);  ul.x = (ua.x >> 16) | (ua.y & 0xffff0000u);
    uh.y = (ua.z & 0xffffu) | (ua.w << 16);  ul.y = (ua.z >> 16) | (ua.w & 0xffff0000u);
    uh.z = (ub.x & 0xffffu) | (ub.y << 16);  ul.z = (ub.x >> 16) | (ub.y & 0xffff0000u);
    uh.w = (ub.z & 0xffffu) | (ub.w << 16);  ul.w = (ub.z >> 16) | (ub.w & 0xffff0000u);
    ah = *(const bf16x8*)&uh;
    al = *(const bf16x8*)&ul;
  };

  issueB(0); issueB(1);
  for (int st = 0; st < NKS_H; ++st) {
    unsigned* sb = bb + (st & 1) * 3072;
    if (st < NKS_H - 1) { asm volatile("s_waitcnt vmcnt(12)" ::: "memory"); }
    else                { asm volatile("s_waitcnt vmcnt(0)"  ::: "memory"); }
    __builtin_amdgcn_sched_barrier(0);
    __builtin_amdgcn_s_barrier();                   // all waves' st-loads landed
    bf16x8 ah, al;
    readA(ah, al, st);
    bf16x8 vbh[6], vbl[6];
#pragma unroll
    for (int f = 0; f < 6; ++f) {
      vbh[f] = *(const bf16x8*)(sb + (f * 2 + 0) * 256 + lofs);
      vbl[f] = *(const bf16x8*)(sb + (f * 2 + 1) * 256 + lofs);
    }
    asm volatile("s_waitcnt lgkmcnt(0)" ::: "memory");
    __builtin_amdgcn_sched_barrier(0);
    __builtin_amdgcn_s_barrier();                   // all waves done reading slot
    if (st + 2 < NKS_H) issueB(st + 2);
#pragma unroll
    for (int jl = 0; jl < 2; ++jl)
#pragma unroll
      for (int c = 0; c < 3; ++c) {
        const int f = c * 2 + jl;
        const int g = (c == 2) ? G2 : c;
        acc[jl][g] = __builtin_amdgcn_mfma_f32_16x16x32_bf16(ah, vbh[f], acc[jl][g], 0, 0, 0);
        acc[jl][g] = __builtin_amdgcn_mfma_f32_16x16x32_bf16(al, vbh[f], acc[jl][g], 0, 0, 0);
        acc[jl][g] = __builtin_amdgcn_mfma_f32_16x16x32_bf16(ah, vbl[f], acc[jl][g], 0, 0, 0);
      }
  }
}

// x-input gate tile (nks=3): x is an immutable input -> plain cached loads.
template <int G2>
__device__ __forceinline__ void gemm_x(
    f32x4 acc[2][4],
    const __hip_bfloat16* __restrict__ WH, const __hip_bfloat16* __restrict__ WL,
    const float* __restrict__ X, int tstep, int b0, int j0, int tid)
{
  const int wv = tid >> 6, lane = tid & 63, quad = lane >> 4, l15 = lane & 15;
  const int ms = wv & 1, jh = wv >> 1;
  const int arow = b0 + ms * 16 + l15;

  unsigned boff[6];
#pragma unroll
  for (int c = 0; c < 3; ++c)
#pragma unroll
    for (int jl = 0; jl < 2; ++jl) {
      const int jb = c * 32 + (j0 >> 4) + jh * 2 + jl;
      boff[c * 2 + jl] = (unsigned)((jb * NKS_X) * 64 + lane) * 8u;
    }
  const float* arp = X + ((size_t)arow * NT + tstep) * NC;

  float a[3][8];
#pragma unroll
  for (int st = 0; st < 3; ++st) {
    const int k0 = st * 32 + (quad << 3);
#pragma unroll
    for (int e = 0; e < 8; ++e) a[st][e] = (k0 + e < NC) ? arp[k0 + e] : 0.f;
  }

  uint4 bh0[6], bl0[6], bh1[6], bl1[6];
  auto loadB = [&](uint4 (&bh)[6], uint4 (&bl)[6], int st) {
    const unsigned so = (unsigned)st * 512u;
#pragma unroll
    for (int f = 0; f < 6; ++f) {
      bh[f] = *(const uint4*)(WH + boff[f] + so);
      bl[f] = *(const uint4*)(WL + boff[f] + so);
    }
  };
  auto comp = [&](const uint4 (&bh)[6], const uint4 (&bl)[6], const float (&av)[8]) {
    float4 v0, v1;
    v0.x = av[0]; v0.y = av[1]; v0.z = av[2]; v0.w = av[3];
    v1.x = av[4]; v1.y = av[5]; v1.z = av[6]; v1.w = av[7];
    ushort4 ph0, pl0, ph1, pl1;
    splitpack4(v0, ph0, pl0);
    splitpack4(v1, ph1, pl1);
    bf16x8 ah, al;
    ((ushort4*)&ah)[0] = ph0; ((ushort4*)&ah)[1] = ph1;
    ((ushort4*)&al)[0] = pl0; ((ushort4*)&al)[1] = pl1;
#pragma unroll
    for (int jl = 0; jl < 2; ++jl)
#pragma unroll
      for (int c = 0; c < 3; ++c) {
        const int f = c * 2 + jl;
        const int g = (c == 2) ? G2 : c;
        const bf16x8 vbh = *(const bf16x8*)&bh[f];
        const bf16x8 vbl = *(const bf16x8*)&bl[f];
        acc[jl][g] = __builtin_amdgcn_mfma_f32_16x16x32_bf16(ah, vbh, acc[jl][g], 0, 0, 0);
        acc[jl][g] = __builtin_amdgcn_mfma_f32_16x16x32_bf16(al, vbh, acc[jl][g], 0, 0, 0);
        acc[jl][g] = __builtin_amdgcn_mfma_f32_16x16x32_bf16(ah, vbl, acc[jl][g], 0, 0, 0);
      }
  };

  loadB(bh0, bl0, 0); loadB(bh1, bl1, 1);
  comp(bh0, bl0, a[0]);
  loadB(bh0, bl0, 2);
  comp(bh1, bl1, a[1]);
  comp(bh0, bl0, a[2]);
}

// GRU elementwise. h-hold carried in REGISTERS. Window (if any) in LDS ring.
// Cross-WG frag: staged in LDS then contiguous agent-scope store sweep.
__device__ __forceinline__ void ew_gru(
    f32x4 acc[2][4],
    const float* __restrict__ bi, const float* __restrict__ bh,
    float (&hreg)[2][4],
    unsigned* __restrict__ hfrag,
    int b0, int j0, int tid, ushort* winl, int slot,
    unsigned* __restrict__ stg)
{
  const int wv = tid >> 6, lane = tid & 63, quad = lane >> 4, l15 = lane & 15;
  const int ms = wv & 1, jh = wv >> 1;
  const int bb0 = b0 >> 4, jcb = j0 >> 5;
  __syncthreads();   // staging buffer may still be read by lagging gemm threads
#pragma unroll
  for (int jlf = 0; jlf < 2; ++jlf) {
    const int j = j0 + jh * 32 + jlf * 16 + l15;
    const float br = bi[j] + bh[j];
    const float bz = bi[NH + j] + bh[NH + j];
    const float bni = bi[2 * NH + j];
    const float bnh = bh[2 * NH + j];
#pragma unroll
    for (int rg = 0; rg < 4; ++rg) {
      const float r = sigmoidf_(acc[jlf][0][rg] + br);
      const float z = sigmoidf_(acc[jlf][1][rg] + bz);
      const float n = tanhf_(acc[jlf][2][rg] + bni + r * (acc[jlf][3][rg] + bnh));
      const float h = hreg[jlf][rg];
      const float hn = (1.f - z) * n + z * h;
      hreg[jlf][rg] = hn;
      const int lanep = (quad * 4 + rg) | ((jlf * 2 + (l15 >> 3)) << 4);
      const int s = (lanep * 8 + (l15 & 7)) ^ ((lanep & 7) << 2);
      stg[ms * 1024 + jh * 512 + s] = packbf(hn);
      if (winl) winl[slot * 2048 + (jlf * 4 + rg) * 256 + tid] = f2bfb(hn);
    }
  }
  __syncthreads();
#pragma unroll
  for (int i = 0; i < 4; ++i) {
    const int q = i * 256 + tid;
    const int chunk = q >> 9, rem = q & 511;
    ull* gb = (ull*)hfrag + ((size_t)(bb0 + chunk) * 16 + jcb) * 256;
    __hip_atomic_store(gb + rem, ((const ull*)stg)[q],
                       __ATOMIC_RELAXED, __HIP_MEMORY_SCOPE_AGENT);
  }
}

// decoder layer-1 EW: h1 hold in registers; window ring in LDS; h1f + tvf
// frags via LDS-staged agent sweep; tvec fp32 via agent stores.
__device__ __forceinline__ void ew_dec1(
    f32x4 acc[2][4], const Params& P, float (&hreg)[2][4],
    int b0, int j0, int tid, int s, unsigned* __restrict__ stg, ushort* winl)
{
  const int wv = tid >> 6, lane = tid & 63, quad = lane >> 4, l15 = lane & 15;
  const int ms = wv & 1, jh = wv >> 1;
  const int bb0 = b0 >> 4, jcb = j0 >> 5;
  const int slot = s % NW;
  float twv[NW];
#pragma unroll
  for (int k = 0; k < NW; ++k) {
    int idx = k - slot - 1; if (idx < 0) idx += NW;
    twv[k] = P.tw[idx];
  }
  const float tw9 = P.tw[NW - 1];
  const float tb0 = P.tb[0];
  __syncthreads();
#pragma unroll
  for (int jlf = 0; jlf < 2; ++jlf) {
    const int j = j0 + jh * 32 + jlf * 16 + l15;
    const float br = P.bih1[j] + P.bhh1[j];
    const float bz = P.bih1[NH + j] + P.bhh1[NH + j];
    const float bni = P.bih1[2 * NH + j];
    const float bnh = P.bhh1[2 * NH + j];
#pragma unroll
    for (int rg = 0; rg < 4; ++rg) {
      const int b = b0 + ms * 16 + quad * 4 + rg;
      const float r = sigmoidf_(acc[jlf][0][rg] + br);
      const float z = sigmoidf_(acc[jlf][1][rg] + bz);
      const float n = tanhf_(acc[jlf][2][rg] + bni + r * (acc[jlf][3][rg] + bnh));
      const float h = hreg[jlf][rg];
      const float hn = (1.f - z) * n + z * h;
      hreg[jlf][rg] = hn;
      const int widx = (jlf * 4 + rg) * 256 + tid;
      winl[slot * 2048 + widx] = f2bfb(hn);
      float ts = tb0 + hn * tw9;
#pragma unroll
      for (int k = 0; k < NW; ++k) {
        if (k == slot) continue;
        ts += bfb2f(winl[k * 2048 + widx]) * twv[k];
      }
      __hip_atomic_store(&P.tvec[(size_t)b * NH + j], ts,
                         __ATOMIC_RELAXED, __HIP_MEMORY_SCOPE_AGENT);
      const int lanep = (quad * 4 + rg) | ((jlf * 2 + (l15 >> 3)) << 4);
      const int sw = (lanep * 8 + (l15 & 7)) ^ ((lanep & 7) << 2);
      stg[ms * 1024 + jh * 512 + sw] = packbf(hn);
      stg[2048 + ms * 1024 + jh * 512 + sw] = packbf(ts);
    }
  }
  __syncthreads();
#pragma unroll
  for (int i = 0; i < 8; ++i) {
    const int q2 = i * 256 + tid;
    const int buf = q2 >> 10, q = q2 & 1023;
    const int chunk = q >> 9, rem = q & 511;
    unsigned* base = buf ? P.tvf : (P.h1f + FRAGN);
    ull* gb = (ull*)base + ((size_t)(bb0 + chunk) * 16 + jcb) * 256;
    __hip_atomic_store(gb + rem, ((const ull*)stg)[q2],
                       __ATOMIC_RELAXED, __HIP_MEMORY_SCOPE_AGENT);
  }
}

__global__ __launch_bounds__(NTHR) void rnn_kernel(Params P) {
  __shared__ __align__(16) unsigned aT[16384];    // 64KB A-tile (+ ew staging)
  __shared__ __align__(16) unsigned Bst[12288];   // 48KB async B staging
  __shared__ __align__(16) ushort wtl[20480];     // 40KB: winl (L1) / tl (L0) overlay
  float* tl = (float*)wtl;
  ushort* winlb = wtl;
  const int tid = threadIdx.x;
  const int wg = blockIdx.x;
  const int grp = wg & 7;
  const size_t gid = (size_t)wg * NTHR + tid;
  const size_t GT = (size_t)NWG * NTHR;
  const int wv = tid >> 6, lane = tid & 63, l15 = lane & 15;
  const int jh = wv >> 1;

  // ---- logical roles ----
  const bool isL1 = wg >= 128;
  const int tile = wg & 127;
  const int b0 = (tile >> 3) * BM;
  const int j0 = (tile & 7) * BJ;
  const int bb0 = b0 >> 4;
  const int jidx = tile & 7;
  const int cluster = tile >> 3;                 // 16 independent b-block clusters
  unsigned* ccnt = P.cbar + (size_t)cluster * 16;

  // ---- init: build swizzled split-bf16 weights ----
  for (size_t f = gid; f < (size_t)G3 * CP / 8; f += GT) {
    const int ln = (int)(f & 63), blk = (int)(f >> 6);
    const int ks = blk % NKS_X, jb = blk / NKS_X;
    const int r = jb * 16 + (ln & 15);
    const int k0 = ks * 32 + ((ln >> 4) << 3);
#pragma unroll
    for (int e = 0; e < 8; ++e) {
      const int k = k0 + e;
      split2(k < NC ? P.Wih0[(size_t)r * NC + k] : 0.f,
             P.Wih0h[f * 8 + e], P.Wih0l[f * 8 + e]);
    }
  }
  {
    const float* srcs[3] = { P.Whh0, P.Wih1, P.Whh1 };
    __hip_bfloat16* dhs[3] = { P.Whh0H, P.Wih1H, P.Whh1H };
    __hip_bfloat16* dls[3] = { P.Whh0L, P.Wih1L, P.Whh1L };
#pragma unroll
    for (int m = 0; m < 3; ++m) {
      const float* __restrict__ W = srcs[m];
      __hip_bfloat16* __restrict__ DH = dhs[m];
      __hip_bfloat16* __restrict__ DL = dls[m];
      for (size_t f = gid; f < (size_t)G3 * NH / 8; f += GT) {
        const int ln = (int)(f & 63), blk = (int)(f >> 6);
        const int ks = blk & 15, jb = blk >> 4;
        const int r = jb * 16 + (ln & 15);
        const int k0 = ks * 32 + ((ln >> 4) << 3);
        const float* src = W + (size_t)r * NH + k0;
        ushort4 h0v, l0v, h1v, l1v;
        splitpack4(*(const float4*)(src), h0v, l0v);
        splitpack4(*(const float4*)(src + 4), h1v, l1v);
        *(ushort4*)(DH + f * 8)     = h0v;
        *(ushort4*)(DH + f * 8 + 4) = h1v;
        *(ushort4*)(DL + f * 8)     = l0v;
        *(ushort4*)(DL + f * 8 + 4) = l1v;
      }
    }
  }
  for (size_t f = gid; f < (size_t)G3 * NH / 8; f += GT) {
    const int ln = (int)(f & 63), blk = (int)(f >> 6);
    const int ks = blk & 15, jb = blk >> 4;
    const int r = jb * 16 + (ln & 15);
    const int k0 = ks * 32 + ((ln >> 4) << 3);
    float s[8] = {0.f, 0.f, 0.f, 0.f, 0.f, 0.f, 0.f, 0.f};
    for (int c = 0; c < NC; ++c) {
      const float a = P.Wih0[(size_t)r * NC + c];
      const float4 w0 = *(const float4*)(P.sw + (size_t)c * NH + k0);
      const float4 w1 = *(const float4*)(P.sw + (size_t)c * NH + k0 + 4);
      s[0] += a * w0.x; s[1] += a * w0.y; s[2] += a * w0.z; s[3] += a * w0.w;
      s[4] += a * w1.x; s[5] += a * w1.y; s[6] += a * w1.z; s[7] += a * w1.w;
    }
#pragma unroll
    for (int e = 0; e < 8; ++e) split2(s[e], P.Wch[f * 8 + e], P.Wcl[f * 8 + e]);
  }
  for (size_t i = gid; i < (size_t)G3; i += GT) {
    float a = 0.f;
    for (int c = 0; c < NC; ++c) a += P.Wih0[i * NC + c] * P.sb[c];
    P.cb[i] = a;
  }
  // ---- role-based zeroing via agent stores ----
  {
    unsigned* z = (!isL1 ? P.h0f : (P.h1f + FRAGN)) + (size_t)bb0 * 8192 + (size_t)jidx * 2048;
    for (int i = tid; i < 2048; i += NTHR)
      __hip_atomic_store(z + i, 0u, __ATOMIC_RELAXED, __HIP_MEMORY_SCOPE_AGENT);
  }
  gbar_init(P.barL, P.barG, tid, grp);   // one-time global release barrier

  unsigned ph = 0;
  float G[2][3][4];
  float hreg[2][4] = {{0.f, 0.f, 0.f, 0.f}, {0.f, 0.f, 0.f, 0.f}};

  // ---- encoder: pipelined L0/L1, one cluster barrier per iteration ----
  for (int t = 0; t <= NT; ++t) {
    const int cur = t & 1;
    f32x4 acc[2][4];
    if (!isL1) {
      if (t < NT) {
        zacc(acc);
        bulk_a(aT, P.h0f + (size_t)cur * FRAGN, bb0, tid);
        gemm_x<2>(acc, P.Wih0h, P.Wih0l, P.x, t, b0, j0, tid);
        __syncthreads();
        gemm_lds<3>(acc, P.Whh0H, P.Whh0L, aT, Bst, j0, tid);
        ew_gru(acc, P.bih0, P.bhh0, hreg, P.h0f + (size_t)(cur ^ 1) * FRAGN,
               b0, j0, tid, nullptr, 0, aT);
      } else {
        zacc(acc);
        gemm_x<2>(acc, P.Wih0h, P.Wih0l, P.x, NT - 1, b0, j0, tid);
#pragma unroll
        for (int jlf = 0; jlf < 2; ++jlf)
#pragma unroll
          for (int c = 0; c < 3; ++c)
#pragma unroll
            for (int rg = 0; rg < 4; ++rg) G[jlf][c][rg] = acc[jlf][c][rg];
      }
    } else {
      if (t >= 1) {
        zacc(acc);
        bulk_a(aT, P.h0f + (size_t)cur * FRAGN, bb0, tid);
        __syncthreads();
        gemm_lds<2>(acc, P.Wih1H, P.Wih1L, aT, Bst, j0, tid);
        __syncthreads();
        bulk_a(aT, P.h1f + (size_t)cur * FRAGN, bb0, tid);
        __syncthreads();
        gemm_lds<3>(acc, P.Whh1H, P.Whh1L, aT, Bst, j0, tid);
        ew_gru(acc, P.bih1, P.bhh1, hreg, P.h1f + (size_t)(cur ^ 1) * FRAGN,
               b0, j0, tid, (t >= 119) ? winlb : nullptr, t - 119, aT);
      }
    }
    xbar(ccnt, ph, tid);
  }

  int d0 = 0;

  float cbr[2][3];
  float Freg[2];
  const int frow = wg * 4;   // L0 frame rows
  if (!isL1) {
#pragma unroll
    for (int jlf = 0; jlf < 2; ++jlf)
#pragma unroll
      for (int c = 0; c < 3; ++c)
        cbr[jlf][c] = P.cb[c * NH + j0 + jh * 32 + jlf * 16 + l15];
#pragma unroll
    for (int v = 0; v < 2; ++v) {
      const int t2 = tid + v * NTHR;
      if (t2 < 4 * NC) {
        const int bl = t2 / NC, c = t2 - bl * NC, b = frow + bl;
        Freg[v] = P.x[((size_t)b * NT + (NT - 1)) * NC + c];
      }
    }
  }

  auto frame_out = [&](int sout) {
    const float* tvb = P.tvec + (size_t)frow * NH;
    *(float4*)&tl[tid * 8] = cload4(tvb + tid * 8);
    *(float4*)&tl[tid * 8 + 4] = cload4(tvb + tid * 8 + 4);
    __syncthreads();
#pragma unroll
    for (int v = 0; v < 2; ++v) {
      const int t2 = tid + v * NTHR;
      if (t2 < 4 * NC) {
        const int bl = t2 / NC, c = t2 - bl * NC, b = frow + bl;
        float f = Freg[v] + P.sb[c];
        const float4* swr = (const float4*)(P.sw + (size_t)c * NH);
        const float4* tr = (const float4*)(tl + bl * NH);
#pragma unroll 8
        for (int h4 = 0; h4 < NH / 4; ++h4) {
          float4 tv = tr[h4], wv4 = swr[h4];
          f += tv.x * wv4.x + tv.y * wv4.y + tv.z * wv4.z + tv.w * wv4.w;
        }
        Freg[v] = f;
        __builtin_nontemporal_store(f, &P.out[((size_t)b * NT + sout) * NC + c]);
      }
    }
    __syncthreads();
  };

  // ---- decoder: 2 cluster barriers per step ----
  for (int s = 0; s < NT; ++s) {
    f32x4 acc[2][4];
    if (!isL1) {
      zacc(acc);
      if (s >= 1) {
        frame_out(s - 1);
        bulk_a(aT, P.tvf, bb0, tid);
        __syncthreads();
        gemm_lds<2>(acc, P.Wch, P.Wcl, aT, Bst, j0, tid);
        __syncthreads();
      }
      bulk_a(aT, P.h0f + (size_t)d0 * FRAGN, bb0, tid);
      __syncthreads();
#pragma unroll
      for (int jlf = 0; jlf < 2; ++jlf)
#pragma unroll
        for (int c = 0; c < 3; ++c)
#pragma unroll
          for (int rg = 0; rg < 4; ++rg) {
            float g = G[jlf][c][rg] + acc[jlf][c][rg] + (s >= 1 ? cbr[jlf][c] : 0.f);
            G[jlf][c][rg] = g;
            acc[jlf][c][rg] = g;
          }
      gemm_lds<3>(acc, P.Whh0H, P.Whh0L, aT, Bst, j0, tid);
      ew_gru(acc, P.bih0, P.bhh0, hreg, P.h0f + (size_t)(d0 ^ 1) * FRAGN,
             b0, j0, tid, nullptr, 0, aT);
    } else {
      zacc(acc);
      bulk_a(aT, P.h1f + (size_t)FRAGN, bb0, tid);
      __syncthreads();
      gemm_lds<3>(acc, P.Whh1H, P.Whh1L, aT, Bst, j0, tid);
      __syncthreads();
    }
    xbar(ccnt, ph, tid);
    if (isL1) {
      bulk_a(aT, P.h0f + (size_t)(d0 ^ 1) * FRAGN, bb0, tid);
      __syncthreads();
      gemm_lds<2>(acc, P.Wih1H, P.Wih1L, aT, Bst, j0, tid);
      ew_dec1(acc, P, hreg, b0, j0, tid, s, aT, winlb);
    }
    xbar(ccnt, ph, tid);
    d0 ^= 1;
  }
  if (!isL1) frame_out(NT - 1);
}

extern "C" void kernel_launch(void* const* d_in, const int* in_sizes, int n_in,
                              void* d_out, int out_size, void* d_ws, size_t ws_size,
                              hipStream_t stream) {
  (void)in_sizes; (void)n_in; (void)out_size; (void)ws_size;
  Params P;
  P.x    = (const float*)d_in[0];
  P.Wih0 = (const float*)d_in[1];
  P.Whh0 = (const float*)d_in[2];
  P.bih0 = (const float*)d_in[3];
  P.bhh0 = (const float*)d_in[4];
  P.Wih1 = (const float*)d_in[5];
  P.Whh1 = (const float*)d_in[6];
  P.bih1 = (const float*)d_in[7];
  P.bhh1 = (const float*)d_in[8];
  P.tw   = (const float*)d_in[9];
  P.tb   = (const float*)d_in[10];
  P.sw   = (const float*)d_in[11];
  P.sb   = (const float*)d_in[12];
  P.out  = (float*)d_out;

  char* w = (char*)d_ws;
  size_t used = 0;
  auto take = [&](size_t bytes) {
    char* p = w + used;
    used += (bytes + 255) & ~(size_t)255;
    return p;
  };
  unsigned* bar = (unsigned*)take(4096);
  P.barL  = bar;            // 8 groups * 32-stride u32 = 1024B
  P.barG  = bar + 256;
  P.cbar  = bar + 320;      // 16 clusters * 16 u32 (64B stride)
  P.Wih0h = (__hip_bfloat16*)take((size_t)G3 * CP * 2);
  P.Wih0l = (__hip_bfloat16*)take((size_t)G3 * CP * 2);
  P.Wch   = (__hip_bfloat16*)take((size_t)G3 * NH * 2);
  P.Wcl   = (__hip_bfloat16*)take((size_t)G3 * NH * 2);
  P.Whh0H = (__hip_bfloat16*)take((size_t)G3 * NH * 2);
  P.Whh0L = (__hip_bfloat16*)take((size_t)G3 * NH * 2);
  P.Wih1H = (__hip_bfloat16*)take((size_t)G3 * NH * 2);
  P.Wih1L = (__hip_bfloat16*)take((size_t)G3 * NH * 2);
  P.Whh1H = (__hip_bfloat16*)take((size_t)G3 * NH * 2);
  P.Whh1L = (__hip_bfloat16*)take((size_t)G3 * NH * 2);
  P.cb    = (float*)take((size_t)G3 * 4);
  P.tvec  = (float*)take((size_t)NB * NH * 4);
  P.h0f   = (unsigned*)take((size_t)2 * FRAGN * 4);
  P.h1f   = (unsigned*)take((size_t)2 * FRAGN * 4);
  P.tvf   = (unsigned*)take((size_t)FRAGN * 4);

  hipMemsetAsync(d_ws, 0, 4096, stream);
  rnn_kernel<<<dim3(NWG), dim3(NTHR), 0, stream>>>(P);
}

// Round 8
// 15994.801 us; speedup vs baseline: 3.5742x; 1.0329x over previous
//
#include <hip/hip_runtime.h>
#include <hip/hip_bf16.h>

typedef __attribute__((ext_vector_type(8))) short bf16x8;
typedef __attribute__((ext_vector_type(4))) float f32x4;
typedef unsigned long long ull;

#define NB 512      // batch
#define NT 128      // timesteps
#define NC 66       // input channels
#define NH 512      // hidden
#define NW 10       // window
#define CP 96       // padded C (3 k-stages of 32)
#define BM 32       // batch tile
#define BJ 64       // j (h-dim) tile
#define NWG 256
#define NTHR 256
#define G3 1536     // 3*NH
#define NKS_H 16    // NH/32 k-stages
#define NKS_X 3     // CP/32 k-stages
#define FRAGN (NB * NH)   // u32 elems per frag buffer (1MB)

struct Params {
  const float *x, *Wih0, *Whh0, *bih0, *bhh0, *Wih1, *Whh1, *bih1, *bhh1, *tw, *tb, *sw, *sb;
  float *out;
  unsigned *barL, *barG;             // one-time global init barrier
  unsigned *cbar;                    // per-cluster (16x) phase barrier counters, 64B stride
  __hip_bfloat16 *Wih0h, *Wih0l;     // layer0 input weights, swizzled split, nks=3
  __hip_bfloat16 *Wch, *Wcl;         // composed Wc = Wih0 @ sw, swizzled split, nks=16
  __hip_bfloat16 *Whh0H, *Whh0L;     // swizzled split, nks=16
  __hip_bfloat16 *Wih1H, *Wih1L;
  __hip_bfloat16 *Whh1H, *Whh1L;
  float *cb;                         // cb = Wih0 @ sb  [G3]
  float *tvec;
  unsigned *h0f, *h1f, *tvf;         // packed split-bf16 A-fragment buffers
};

__device__ __forceinline__ float sigmoidf_(float x) { return 1.f / (1.f + __expf(-x)); }
__device__ __forceinline__ float tanhf_(float x) {
  float e = __expf(2.f * x);
  return (e - 1.f) / (e + 1.f);
}
__device__ __forceinline__ void split2(float v, __hip_bfloat16& h, __hip_bfloat16& l) {
  h = __float2bfloat16(v);
  l = __float2bfloat16(v - __bfloat162float(h));
}
__device__ __forceinline__ unsigned short bfbits(__hip_bfloat16 h) { return *(unsigned short*)&h; }
__device__ __forceinline__ void splitpack4(float4 v, ushort4& ph, ushort4& pl) {
  __hip_bfloat16 h, l;
  split2(v.x, h, l); ph.x = bfbits(h); pl.x = bfbits(l);
  split2(v.y, h, l); ph.y = bfbits(h); pl.y = bfbits(l);
  split2(v.z, h, l); ph.z = bfbits(h); pl.z = bfbits(l);
  split2(v.w, h, l); ph.w = bfbits(h); pl.w = bfbits(l);
}
// packed split-bf16: lo16 = hi-part, hi16 = lo-part
__device__ __forceinline__ unsigned packbf(float v) {
  __hip_bfloat16 h, l; split2(v, h, l);
  return (unsigned)bfbits(h) | ((unsigned)bfbits(l) << 16);
}
__device__ __forceinline__ unsigned short f2bfb(float v) {
  __hip_bfloat16 h = __float2bfloat16(v);
  return bfbits(h);
}
__device__ __forceinline__ float bfb2f(unsigned short u) {
  __hip_bfloat16 h = *(__hip_bfloat16*)&u;
  return __bfloat162float(h);
}

// async global->LDS, 16B/lane; LDS dest = wave-uniform base + lane*16
__device__ __forceinline__ void gld_lds16(const void* g, void* l) {
  __builtin_amdgcn_global_load_lds(
      (const __attribute__((address_space(1))) unsigned*)g,
      (__attribute__((address_space(3))) unsigned*)l, 16, 0, 0);
}

// device-coherent (cache-bypass) loads for cross-WG activation data
__device__ __forceinline__ float4 cload4(const float* p) {
  ull a = __hip_atomic_load((const ull*)p,       __ATOMIC_RELAXED, __HIP_MEMORY_SCOPE_AGENT);
  ull b = __hip_atomic_load(((const ull*)p) + 1, __ATOMIC_RELAXED, __HIP_MEMORY_SCOPE_AGENT);
  float4 r;
  ((ull*)&r)[0] = a;
  ((ull*)&r)[1] = b;
  return r;
}

// One-time global barrier after init: RELEASE -> L2 writeback so plain-stored
// init data (weights) is chip-visible. Poll: barG reaches 8.
__device__ __forceinline__ void gbar_init(unsigned* barL, unsigned* barG, int tid, int grp) {
  asm volatile("s_waitcnt vmcnt(0)" ::: "memory");
  __syncthreads();
  if (tid == 0) {
    unsigned old = __hip_atomic_fetch_add(&barL[grp * 32], 1u, __ATOMIC_RELEASE,
                                          __HIP_MEMORY_SCOPE_AGENT);
    if (old == 31u)
      __hip_atomic_fetch_add(barG, 1u, __ATOMIC_RELAXED, __HIP_MEMORY_SCOPE_AGENT);
    while (__hip_atomic_load(barG, __ATOMIC_RELAXED, __HIP_MEMORY_SCOPE_AGENT) < 8u)
      __builtin_amdgcn_s_sleep(2);
  }
  __syncthreads();
  asm volatile("" ::: "memory");
}

// 16-WG cluster barrier (logical IDs only). All cross-WG data moves via
// agent-scope ops; vmcnt(0) drains them before arrival.
__device__ __forceinline__ void xbar(unsigned* cnt, unsigned& ph, int tid) {
  asm volatile("s_waitcnt vmcnt(0)" ::: "memory");
  __syncthreads();
  ++ph;
  if (tid == 0) {
    __hip_atomic_fetch_add(cnt, 1u, __ATOMIC_RELAXED, __HIP_MEMORY_SCOPE_AGENT);
    while (__hip_atomic_load(cnt, __ATOMIC_RELAXED, __HIP_MEMORY_SCOPE_AGENT) < ph * 16u)
      __builtin_amdgcn_s_sleep(1);
  }
  __syncthreads();
  asm volatile("" ::: "memory");
}

__device__ __forceinline__ void zacc(f32x4 acc[2][4]) {
#pragma unroll
  for (int i = 0; i < 2; ++i)
#pragma unroll
    for (int g = 0; g < 4; ++g) {
      acc[i][g][0] = 0.f; acc[i][g][1] = 0.f; acc[i][g][2] = 0.f; acc[i][g][3] = 0.f;
    }
}

// Bulk A-tile loader: 64KB contiguous from the frag buffer into LDS.
// Pipelined 4 groups of 8x8B agent-scope loads per thread.
__device__ __forceinline__ void bulk_a(unsigned* __restrict__ alds,
                                       const unsigned* __restrict__ frag,
                                       int bb0, int tid) {
  const ull* g = (const ull*)(frag + (size_t)bb0 * 8192);
  ull* d = (ull*)alds;
  ull va[8], vb[8];
  auto ld8 = [&](ull (&a)[8], int grp) {
#pragma unroll
    for (int i = 0; i < 8; ++i)
      a[i] = __hip_atomic_load(g + (grp * 8 + i) * 256 + tid,
                               __ATOMIC_RELAXED, __HIP_MEMORY_SCOPE_AGENT);
  };
  auto st8 = [&](ull (&a)[8], int grp) {
#pragma unroll
    for (int i = 0; i < 8; ++i) d[(grp * 8 + i) * 256 + tid] = a[i];
  };
  ld8(va, 0); ld8(vb, 1);
  st8(va, 0); ld8(va, 2);
  st8(vb, 1); ld8(vb, 3);
  st8(va, 2); st8(vb, 3);
}

// (BM x 3*BJ) gate tile, nks=16: A from LDS frag tile; B staged via ASYNC
// global_load_lds into a double-buffered LDS slot (counted vmcnt, zero data
// VGPRs -> deep in-flight pipeline). Two s_barriers/stage bound wave skew so
// slot reuse cannot race. Math order identical to prior rounds.
template <int G2>
__device__ __forceinline__ void gemm_lds(
    f32x4 acc[2][4],
    const __hip_bfloat16* __restrict__ WH, const __hip_bfloat16* __restrict__ WL,
    const unsigned* __restrict__ aT, unsigned* __restrict__ Bst, int j0, int tid)
{
  const int wv = tid >> 6, lane = tid & 63;
  const int ms = wv & 1, jh = wv >> 1;

  const __hip_bfloat16* wsrc[12];
#pragma unroll
  for (int c = 0; c < 3; ++c)
#pragma unroll
    for (int jl = 0; jl < 2; ++jl) {
      const int jb = c * 32 + (j0 >> 4) + jh * 2 + jl;
      const unsigned bo = (unsigned)((jb * NKS_H) * 64 + lane) * 8u;
      wsrc[(c * 2 + jl) * 2 + 0] = WH + bo;
      wsrc[(c * 2 + jl) * 2 + 1] = WL + bo;
    }
  unsigned* const bb = Bst + jh * 6144;            // [jh][slot2][chunk12][256 u32]
  const unsigned* ab = aT + ms * 8192;
  const unsigned i0 = ((unsigned)(lane * 8)) ^ ((unsigned)(lane & 7) << 2);
  const int lofs = lane * 4;

  auto issueB = [&](int st) {
    unsigned* sb = bb + (st & 1) * 3072;
#pragma unroll
    for (int k = 0; k < 12; ++k)
      gld_lds16(wsrc[k] + (size_t)st * 512, sb + k * 256);
  };
  auto readA = [&](bf16x8& ah, bf16x8& al, int st) {
    const unsigned* ap = ab + st * 512;
    const uint4 ua = *(const uint4*)(ap + i0);          // elems e0..3
    const uint4 ub = *(const uint4*)(ap + (i0 ^ 4u));   // elems e4..7
    uint4 uh, ul;
    uh.x = (ua.x & 0xffffu) | (ua.y << 16);  ul.x = (ua.x >> 16) | (ua.y & 0xffff0000u);
    uh.y = (ua.z & 0xffffu) | (ua.w << 16);  ul.y = (ua.z >> 16) | (ua.w & 0xffff0000u);
    uh.z = (ub.x & 0xffffu) | (ub.y << 16);  ul.z = (ub.x >> 16) | (ub.y & 0xffff0000u);
    uh.w = (ub.z & 0xffffu) | (ub.w << 16);  ul.w = (ub.z >> 16) | (ub.w & 0xffff0000u);
    ah = *(const bf16x8*)&uh;
    al = *(const bf16x8*)&ul;
  };

  issueB(0); issueB(1);
  for (int st = 0; st < NKS_H; ++st) {
    unsigned* sb = bb + (st & 1) * 3072;
    if (st < NKS_H - 1) { asm volatile("s_waitcnt vmcnt(12)" ::: "memory"); }
    else                { asm volatile("s_waitcnt vmcnt(0)"  ::: "memory"); }
    __builtin_amdgcn_sched_barrier(0);
    __builtin_amdgcn_s_barrier();                   // all waves' st-loads landed
    bf16x8 ah, al;
    readA(ah, al, st);
    bf16x8 vbh[6], vbl[6];
#pragma unroll
    for (int f = 0; f < 6; ++f) {
      vbh[f] = *(const bf16x8*)(sb + (f * 2 + 0) * 256 + lofs);
      vbl[f] = *(const bf16x8*)(sb + (f * 2 + 1) * 256 + lofs);
    }
    asm volatile("s_waitcnt lgkmcnt(0)" ::: "memory");
    __builtin_amdgcn_sched_barrier(0);
    __builtin_amdgcn_s_barrier();                   // all waves done reading slot
    if (st + 2 < NKS_H) issueB(st + 2);
#pragma unroll
    for (int jl = 0; jl < 2; ++jl)
#pragma unroll
      for (int c = 0; c < 3; ++c) {
        const int f = c * 2 + jl;
        const int g = (c == 2) ? G2 : c;
        acc[jl][g] = __builtin_amdgcn_mfma_f32_16x16x32_bf16(ah, vbh[f], acc[jl][g], 0, 0, 0);
        acc[jl][g] = __builtin_amdgcn_mfma_f32_16x16x32_bf16(al, vbh[f], acc[jl][g], 0, 0, 0);
        acc[jl][g] = __builtin_amdgcn_mfma_f32_16x16x32_bf16(ah, vbl[f], acc[jl][g], 0, 0, 0);
      }
  }
}

// x-input gate tile (nks=3): x is an immutable input -> plain cached loads.
template <int G2>
__device__ __forceinline__ void gemm_x(
    f32x4 acc[2][4],
    const __hip_bfloat16* __restrict__ WH, const __hip_bfloat16* __restrict__ WL,
    const float* __restrict__ X, int tstep, int b0, int j0, int tid)
{
  const int wv = tid >> 6, lane = tid & 63, quad = lane >> 4, l15 = lane & 15;
  const int ms = wv & 1, jh = wv >> 1;
  const int arow = b0 + ms * 16 + l15;

  unsigned boff[6];
#pragma unroll
  for (int c = 0; c < 3; ++c)
#pragma unroll
    for (int jl = 0; jl < 2; ++jl) {
      const int jb = c * 32 + (j0 >> 4) + jh * 2 + jl;
      boff[c * 2 + jl] = (unsigned)((jb * NKS_X) * 64 + lane) * 8u;
    }
  const float* arp = X + ((size_t)arow * NT + tstep) * NC;

  float a[3][8];
#pragma unroll
  for (int st = 0; st < 3; ++st) {
    const int k0 = st * 32 + (quad << 3);
#pragma unroll
    for (int e = 0; e < 8; ++e) a[st][e] = (k0 + e < NC) ? arp[k0 + e] : 0.f;
  }

  uint4 bh0[6], bl0[6], bh1[6], bl1[6];
  auto loadB = [&](uint4 (&bh)[6], uint4 (&bl)[6], int st) {
    const unsigned so = (unsigned)st * 512u;
#pragma unroll
    for (int f = 0; f < 6; ++f) {
      bh[f] = *(const uint4*)(WH + boff[f] + so);
      bl[f] = *(const uint4*)(WL + boff[f] + so);
    }
  };
  auto comp = [&](const uint4 (&bh)[6], const uint4 (&bl)[6], const float (&av)[8]) {
    float4 v0, v1;
    v0.x = av[0]; v0.y = av[1]; v0.z = av[2]; v0.w = av[3];
    v1.x = av[4]; v1.y = av[5]; v1.z = av[6]; v1.w = av[7];
    ushort4 ph0, pl0, ph1, pl1;
    splitpack4(v0, ph0, pl0);
    splitpack4(v1, ph1, pl1);
    bf16x8 ah, al;
    ((ushort4*)&ah)[0] = ph0; ((ushort4*)&ah)[1] = ph1;
    ((ushort4*)&al)[0] = pl0; ((ushort4*)&al)[1] = pl1;
#pragma unroll
    for (int jl = 0; jl < 2; ++jl)
#pragma unroll
      for (int c = 0; c < 3; ++c) {
        const int f = c * 2 + jl;
        const int g = (c == 2) ? G2 : c;
        const bf16x8 vbh = *(const bf16x8*)&bh[f];
        const bf16x8 vbl = *(const bf16x8*)&bl[f];
        acc[jl][g] = __builtin_amdgcn_mfma_f32_16x16x32_bf16(ah, vbh, acc[jl][g], 0, 0, 0);
        acc[jl][g] = __builtin_amdgcn_mfma_f32_16x16x32_bf16(al, vbh, acc[jl][g], 0, 0, 0);
        acc[jl][g] = __builtin_amdgcn_mfma_f32_16x16x32_bf16(ah, vbl, acc[jl][g], 0, 0, 0);
      }
  };

  loadB(bh0, bl0, 0); loadB(bh1, bl1, 1);
  comp(bh0, bl0, a[0]);
  loadB(bh0, bl0, 2);
  comp(bh1, bl1, a[1]);
  comp(bh0, bl0, a[2]);
}

// GRU elementwise. h-hold carried in REGISTERS. Window (if any) in LDS ring.
// Cross-WG frag: staged in LDS then contiguous agent-scope store sweep.
__device__ __forceinline__ void ew_gru(
    f32x4 acc[2][4],
    const float* __restrict__ bi, const float* __restrict__ bh,
    float (&hreg)[2][4],
    unsigned* __restrict__ hfrag,
    int b0, int j0, int tid, ushort* winl, int slot,
    unsigned* __restrict__ stg)
{
  const int wv = tid >> 6, lane = tid & 63, quad = lane >> 4, l15 = lane & 15;
  const int ms = wv & 1, jh = wv >> 1;
  const int bb0 = b0 >> 4, jcb = j0 >> 5;
  __syncthreads();   // staging buffer may still be read by lagging gemm threads
#pragma unroll
  for (int jlf = 0; jlf < 2; ++jlf) {
    const int j = j0 + jh * 32 + jlf * 16 + l15;
    const float br = bi[j] + bh[j];
    const float bz = bi[NH + j] + bh[NH + j];
    const float bni = bi[2 * NH + j];
    const float bnh = bh[2 * NH + j];
#pragma unroll
    for (int rg = 0; rg < 4; ++rg) {
      const float r = sigmoidf_(acc[jlf][0][rg] + br);
      const float z = sigmoidf_(acc[jlf][1][rg] + bz);
      const float n = tanhf_(acc[jlf][2][rg] + bni + r * (acc[jlf][3][rg] + bnh));
      const float h = hreg[jlf][rg];
      const float hn = (1.f - z) * n + z * h;
      hreg[jlf][rg] = hn;
      const int lanep = (quad * 4 + rg) | ((jlf * 2 + (l15 >> 3)) << 4);
      const int s = (lanep * 8 + (l15 & 7)) ^ ((lanep & 7) << 2);
      stg[ms * 1024 + jh * 512 + s] = packbf(hn);
      if (winl) winl[slot * 2048 + (jlf * 4 + rg) * 256 + tid] = f2bfb(hn);
    }
  }
  __syncthreads();
#pragma unroll
  for (int i = 0; i < 4; ++i) {
    const int q = i * 256 + tid;
    const int chunk = q >> 9, rem = q & 511;
    ull* gb = (ull*)hfrag + ((size_t)(bb0 + chunk) * 16 + jcb) * 256;
    __hip_atomic_store(gb + rem, ((const ull*)stg)[q],
                       __ATOMIC_RELAXED, __HIP_MEMORY_SCOPE_AGENT);
  }
}

// decoder layer-1 EW: h1 hold in registers; window ring in LDS; h1f + tvf
// frags via LDS-staged agent sweep; tvec fp32 via agent stores.
__device__ __forceinline__ void ew_dec1(
    f32x4 acc[2][4], const Params& P, float (&hreg)[2][4],
    int b0, int j0, int tid, int s, unsigned* __restrict__ stg, ushort* winl)
{
  const int wv = tid >> 6, lane = tid & 63, quad = lane >> 4, l15 = lane & 15;
  const int ms = wv & 1, jh = wv >> 1;
  const int bb0 = b0 >> 4, jcb = j0 >> 5;
  const int slot = s % NW;
  float twv[NW];
#pragma unroll
  for (int k = 0; k < NW; ++k) {
    int idx = k - slot - 1; if (idx < 0) idx += NW;
    twv[k] = P.tw[idx];
  }
  const float tw9 = P.tw[NW - 1];
  const float tb0 = P.tb[0];
  __syncthreads();
#pragma unroll
  for (int jlf = 0; jlf < 2; ++jlf) {
    const int j = j0 + jh * 32 + jlf * 16 + l15;
    const float br = P.bih1[j] + P.bhh1[j];
    const float bz = P.bih1[NH + j] + P.bhh1[NH + j];
    const float bni = P.bih1[2 * NH + j];
    const float bnh = P.bhh1[2 * NH + j];
#pragma unroll
    for (int rg = 0; rg < 4; ++rg) {
      const int b = b0 + ms * 16 + quad * 4 + rg;
      const float r = sigmoidf_(acc[jlf][0][rg] + br);
      const float z = sigmoidf_(acc[jlf][1][rg] + bz);
      const float n = tanhf_(acc[jlf][2][rg] + bni + r * (acc[jlf][3][rg] + bnh));
      const float h = hreg[jlf][rg];
      const float hn = (1.f - z) * n + z * h;
      hreg[jlf][rg] = hn;
      const int widx = (jlf * 4 + rg) * 256 + tid;
      winl[slot * 2048 + widx] = f2bfb(hn);
      float ts = tb0 + hn * tw9;
#pragma unroll
      for (int k = 0; k < NW; ++k) {
        if (k == slot) continue;
        ts += bfb2f(winl[k * 2048 + widx]) * twv[k];
      }
      __hip_atomic_store(&P.tvec[(size_t)b * NH + j], ts,
                         __ATOMIC_RELAXED, __HIP_MEMORY_SCOPE_AGENT);
      const int lanep = (quad * 4 + rg) | ((jlf * 2 + (l15 >> 3)) << 4);
      const int sw = (lanep * 8 + (l15 & 7)) ^ ((lanep & 7) << 2);
      stg[ms * 1024 + jh * 512 + sw] = packbf(hn);
      stg[2048 + ms * 1024 + jh * 512 + sw] = packbf(ts);
    }
  }
  __syncthreads();
#pragma unroll
  for (int i = 0; i < 8; ++i) {
    const int q2 = i * 256 + tid;
    const int buf = q2 >> 10, q = q2 & 1023;
    const int chunk = q >> 9, rem = q & 511;
    unsigned* base = buf ? P.tvf : (P.h1f + FRAGN);
    ull* gb = (ull*)base + ((size_t)(bb0 + chunk) * 16 + jcb) * 256;
    __hip_atomic_store(gb + rem, ((const ull*)stg)[q2],
                       __ATOMIC_RELAXED, __HIP_MEMORY_SCOPE_AGENT);
  }
}

__global__ __launch_bounds__(NTHR) void rnn_kernel(Params P) {
  __shared__ __align__(16) unsigned aT[16384];    // 64KB A-tile (+ ew staging)
  __shared__ __align__(16) unsigned Bst[12288];   // 48KB async B staging
  __shared__ __align__(16) ushort wtl[20480];     // 40KB: winl (L1) / tl (L0) overlay
  float* tl = (float*)wtl;
  ushort* winlb = wtl;
  const int tid = threadIdx.x;
  const int wg = blockIdx.x;
  const int grp = wg & 7;
  const size_t gid = (size_t)wg * NTHR + tid;
  const size_t GT = (size_t)NWG * NTHR;
  const int wv = tid >> 6, lane = tid & 63, l15 = lane & 15;
  const int jh = wv >> 1;

  // ---- logical roles ----
  const bool isL1 = wg >= 128;
  const int tile = wg & 127;
  const int b0 = (tile >> 3) * BM;
  const int j0 = (tile & 7) * BJ;
  const int bb0 = b0 >> 4;
  const int jidx = tile & 7;
  const int cluster = tile >> 3;                 // 16 independent b-block clusters
  unsigned* ccnt = P.cbar + (size_t)cluster * 16;

  // ---- init: build swizzled split-bf16 weights ----
  for (size_t f = gid; f < (size_t)G3 * CP / 8; f += GT) {
    const int ln = (int)(f & 63), blk = (int)(f >> 6);
    const int ks = blk % NKS_X, jb = blk / NKS_X;
    const int r = jb * 16 + (ln & 15);
    const int k0 = ks * 32 + ((ln >> 4) << 3);
#pragma unroll
    for (int e = 0; e < 8; ++e) {
      const int k = k0 + e;
      split2(k < NC ? P.Wih0[(size_t)r * NC + k] : 0.f,
             P.Wih0h[f * 8 + e], P.Wih0l[f * 8 + e]);
    }
  }
  {
    const float* srcs[3] = { P.Whh0, P.Wih1, P.Whh1 };
    __hip_bfloat16* dhs[3] = { P.Whh0H, P.Wih1H, P.Whh1H };
    __hip_bfloat16* dls[3] = { P.Whh0L, P.Wih1L, P.Whh1L };
#pragma unroll
    for (int m = 0; m < 3; ++m) {
      const float* __restrict__ W = srcs[m];
      __hip_bfloat16* __restrict__ DH = dhs[m];
      __hip_bfloat16* __restrict__ DL = dls[m];
      for (size_t f = gid; f < (size_t)G3 * NH / 8; f += GT) {
        const int ln = (int)(f & 63), blk = (int)(f >> 6);
        const int ks = blk & 15, jb = blk >> 4;
        const int r = jb * 16 + (ln & 15);
        const int k0 = ks * 32 + ((ln >> 4) << 3);
        const float* src = W + (size_t)r * NH + k0;
        ushort4 h0v, l0v, h1v, l1v;
        splitpack4(*(const float4*)(src), h0v, l0v);
        splitpack4(*(const float4*)(src + 4), h1v, l1v);
        *(ushort4*)(DH + f * 8)     = h0v;
        *(ushort4*)(DH + f * 8 + 4) = h1v;
        *(ushort4*)(DL + f * 8)     = l0v;
        *(ushort4*)(DL + f * 8 + 4) = l1v;
      }
    }
  }
  for (size_t f = gid; f < (size_t)G3 * NH / 8; f += GT) {
    const int ln = (int)(f & 63), blk = (int)(f >> 6);
    const int ks = blk & 15, jb = blk >> 4;
    const int r = jb * 16 + (ln & 15);
    const int k0 = ks * 32 + ((ln >> 4) << 3);
    float s[8] = {0.f, 0.f, 0.f, 0.f, 0.f, 0.f, 0.f, 0.f};
    for (int c = 0; c < NC; ++c) {
      const float a = P.Wih0[(size_t)r * NC + c];
      const float4 w0 = *(const float4*)(P.sw + (size_t)c * NH + k0);
      const float4 w1 = *(const float4*)(P.sw + (size_t)c * NH + k0 + 4);
      s[0] += a * w0.x; s[1] += a * w0.y; s[2] += a * w0.z; s[3] += a * w0.w;
      s[4] += a * w1.x; s[5] += a * w1.y; s[6] += a * w1.z; s[7] += a * w1.w;
    }
#pragma unroll
    for (int e = 0; e < 8; ++e) split2(s[e], P.Wch[f * 8 + e], P.Wcl[f * 8 + e]);
  }
  for (size_t i = gid; i < (size_t)G3; i += GT) {
    float a = 0.f;
    for (int c = 0; c < NC; ++c) a += P.Wih0[i * NC + c] * P.sb[c];
    P.cb[i] = a;
  }
  // ---- role-based zeroing via agent stores ----
  {
    unsigned* z = (!isL1 ? P.h0f : (P.h1f + FRAGN)) + (size_t)bb0 * 8192 + (size_t)jidx * 2048;
    for (int i = tid; i < 2048; i += NTHR)
      __hip_atomic_store(z + i, 0u, __ATOMIC_RELAXED, __HIP_MEMORY_SCOPE_AGENT);
  }
  gbar_init(P.barL, P.barG, tid, grp);   // one-time global release barrier

  unsigned ph = 0;
  float G[2][3][4];
  float hreg[2][4] = {{0.f, 0.f, 0.f, 0.f}, {0.f, 0.f, 0.f, 0.f}};
  f32x4 whh[2][4];   // L0 decoder pipeline: saved Whh0 @ h0_s (entries 0,1,3 live)

  // ---- encoder: pipelined L0/L1, one cluster barrier per iteration ----
  for (int t = 0; t <= NT; ++t) {
    const int cur = t & 1;
    f32x4 acc[2][4];
    if (!isL1) {
      if (t < NT) {
        zacc(acc);
        bulk_a(aT, P.h0f + (size_t)cur * FRAGN, bb0, tid);
        gemm_x<2>(acc, P.Wih0h, P.Wih0l, P.x, t, b0, j0, tid);
        __syncthreads();
        gemm_lds<3>(acc, P.Whh0H, P.Whh0L, aT, Bst, j0, tid);
        ew_gru(acc, P.bih0, P.bhh0, hreg, P.h0f + (size_t)(cur ^ 1) * FRAGN,
               b0, j0, tid, nullptr, 0, aT);
      } else {
        // G_0 = x[:,127,:] @ Wih0^T ; and prime the decoder's whh pipeline
        // with Whh0 @ h0_T (h0f buf0 holds h0_T here: cur = 0).
        zacc(acc);
        bulk_a(aT, P.h0f + (size_t)cur * FRAGN, bb0, tid);
        gemm_x<2>(acc, P.Wih0h, P.Wih0l, P.x, NT - 1, b0, j0, tid);
#pragma unroll
        for (int jlf = 0; jlf < 2; ++jlf)
#pragma unroll
          for (int c = 0; c < 3; ++c)
#pragma unroll
            for (int rg = 0; rg < 4; ++rg) G[jlf][c][rg] = acc[jlf][c][rg];
        __syncthreads();
        zacc(whh);
        gemm_lds<3>(whh, P.Whh0H, P.Whh0L, aT, Bst, j0, tid);
      }
    } else {
      if (t >= 1) {
        zacc(acc);
        bulk_a(aT, P.h0f + (size_t)cur * FRAGN, bb0, tid);
        __syncthreads();
        gemm_lds<2>(acc, P.Wih1H, P.Wih1L, aT, Bst, j0, tid);
        __syncthreads();
        bulk_a(aT, P.h1f + (size_t)cur * FRAGN, bb0, tid);
        __syncthreads();
        gemm_lds<3>(acc, P.Whh1H, P.Whh1L, aT, Bst, j0, tid);
        ew_gru(acc, P.bih1, P.bhh1, hreg, P.h1f + (size_t)(cur ^ 1) * FRAGN,
               b0, j0, tid, (t >= 119) ? winlb : nullptr, t - 119, aT);
      }
    }
    xbar(ccnt, ph, tid);
  }

  int d0 = 0;

  float cbr[2][3];
  float Freg[2];
  const int frow = wg * 4;   // L0 frame rows
  if (!isL1) {
#pragma unroll
    for (int jlf = 0; jlf < 2; ++jlf)
#pragma unroll
      for (int c = 0; c < 3; ++c)
        cbr[jlf][c] = P.cb[c * NH + j0 + jh * 32 + jlf * 16 + l15];
#pragma unroll
    for (int v = 0; v < 2; ++v) {
      const int t2 = tid + v * NTHR;
      if (t2 < 4 * NC) {
        const int bl = t2 / NC, c = t2 - bl * NC, b = frow + bl;
        Freg[v] = P.x[((size_t)b * NT + (NT - 1)) * NC + c];
      }
    }
  }

  auto frame_out = [&](int sout) {
    const float* tvb = P.tvec + (size_t)frow * NH;
    *(float4*)&tl[tid * 8] = cload4(tvb + tid * 8);
    *(float4*)&tl[tid * 8 + 4] = cload4(tvb + tid * 8 + 4);
    __syncthreads();
#pragma unroll
    for (int v = 0; v < 2; ++v) {
      const int t2 = tid + v * NTHR;
      if (t2 < 4 * NC) {
        const int bl = t2 / NC, c = t2 - bl * NC, b = frow + bl;
        float f = Freg[v] + P.sb[c];
        const float4* swr = (const float4*)(P.sw + (size_t)c * NH);
        const float4* tr = (const float4*)(tl + bl * NH);
#pragma unroll 8
        for (int h4 = 0; h4 < NH / 4; ++h4) {
          float4 tv = tr[h4], wv4 = swr[h4];
          f += tv.x * wv4.x + tv.y * wv4.y + tv.z * wv4.z + tv.w * wv4.w;
        }
        Freg[v] = f;
        __builtin_nontemporal_store(f, &P.out[((size_t)b * NT + sout) * NC + c]);
      }
    }
    __syncthreads();
  };

  // ---- decoder: rebalanced, 1 gemm/WG per phase, 2 cluster barriers/step ----
  // Phase A: L0: Wc-gemm + G-update + saved-whh add + ew  | L1: Whh1-gemm
  // Phase B: L0: Whh0-gemm on fresh h0f -> whh (for s+1)  | L1: Wih1-gemm + ew_dec1
  for (int s = 0; s < NT; ++s) {
    f32x4 acc[2][4];
    if (!isL1) {
      zacc(acc);
      if (s >= 1) {
        frame_out(s - 1);
        bulk_a(aT, P.tvf, bb0, tid);
        __syncthreads();
        gemm_lds<2>(acc, P.Wch, P.Wcl, aT, Bst, j0, tid);
      }
#pragma unroll
      for (int jlf = 0; jlf < 2; ++jlf) {
#pragma unroll
        for (int c = 0; c < 3; ++c)
#pragma unroll
          for (int rg = 0; rg < 4; ++rg) {
            float g = G[jlf][c][rg] + acc[jlf][c][rg] + (s >= 1 ? cbr[jlf][c] : 0.f);
            G[jlf][c][rg] = g;
            acc[jlf][c][rg] = g;
          }
#pragma unroll
        for (int rg = 0; rg < 4; ++rg) {
          acc[jlf][0][rg] += whh[jlf][0][rg];
          acc[jlf][1][rg] += whh[jlf][1][rg];
          acc[jlf][3][rg]  = whh[jlf][3][rg];
        }
      }
      ew_gru(acc, P.bih0, P.bhh0, hreg, P.h0f + (size_t)(d0 ^ 1) * FRAGN,
             b0, j0, tid, nullptr, 0, aT);
    } else {
      zacc(acc);
      bulk_a(aT, P.h1f + (size_t)FRAGN, bb0, tid);
      __syncthreads();
      gemm_lds<3>(acc, P.Whh1H, P.Whh1L, aT, Bst, j0, tid);
      __syncthreads();
    }
    xbar(ccnt, ph, tid);
    if (!isL1) {
      if (s < NT - 1) {
        bulk_a(aT, P.h0f + (size_t)(d0 ^ 1) * FRAGN, bb0, tid);
        __syncthreads();
        zacc(whh);
        gemm_lds<3>(whh, P.Whh0H, P.Whh0L, aT, Bst, j0, tid);
      }
    } else {
      bulk_a(aT, P.h0f + (size_t)(d0 ^ 1) * FRAGN, bb0, tid);
      __syncthreads();
      gemm_lds<2>(acc, P.Wih1H, P.Wih1L, aT, Bst, j0, tid);
      ew_dec1(acc, P, hreg, b0, j0, tid, s, aT, winlb);
    }
    xbar(ccnt, ph, tid);
    d0 ^= 1;
  }
  if (!isL1) frame_out(NT - 1);
}

extern "C" void kernel_launch(void* const* d_in, const int* in_sizes, int n_in,
                              void* d_out, int out_size, void* d_ws, size_t ws_size,
                              hipStream_t stream) {
  (void)in_sizes; (void)n_in; (void)out_size; (void)ws_size;
  Params P;
  P.x    = (const float*)d_in[0];
  P.Wih0 = (const float*)d_in[1];
  P.Whh0 = (const float*)d_in[2];
  P.bih0 = (const float*)d_in[3];
  P.bhh0 = (const float*)d_in[4];
  P.Wih1 = (const float*)d_in[5];
  P.Whh1 = (const float*)d_in[6];
  P.bih1 = (const float*)d_in[7];
  P.bhh1 = (const float*)d_in[8];
  P.tw   = (const float*)d_in[9];
  P.tb   = (const float*)d_in[10];
  P.sw   = (const float*)d_in[11];
  P.sb   = (const float*)d_in[12];
  P.out  = (float*)d_out;

  char* w = (char*)d_ws;
  size_t used = 0;
  auto take = [&](size_t bytes) {
    char* p = w + used;
    used += (bytes + 255) & ~(size_t)255;
    return p;
  };
  unsigned* bar = (unsigned*)take(4096);
  P.barL  = bar;            // 8 groups * 32-stride u32 = 1024B
  P.barG  = bar + 256;
  P.cbar  = bar + 320;      // 16 clusters * 16 u32 (64B stride)
  P.Wih0h = (__hip_bfloat16*)take((size_t)G3 * CP * 2);
  P.Wih0l = (__hip_bfloat16*)take((size_t)G3 * CP * 2);
  P.Wch   = (__hip_bfloat16*)take((size_t)G3 * NH * 2);
  P.Wcl   = (__hip_bfloat16*)take((size_t)G3 * NH * 2);
  P.Whh0H = (__hip_bfloat16*)take((size_t)G3 * NH * 2);
  P.Whh0L = (__hip_bfloat16*)take((size_t)G3 * NH * 2);
  P.Wih1H = (__hip_bfloat16*)take((size_t)G3 * NH * 2);
  P.Wih1L = (__hip_bfloat16*)take((size_t)G3 * NH * 2);
  P.Whh1H = (__hip_bfloat16*)take((size_t)G3 * NH * 2);
  P.Whh1L = (__hip_bfloat16*)take((size_t)G3 * NH * 2);
  P.cb    = (float*)take((size_t)G3 * 4);
  P.tvec  = (float*)take((size_t)NB * NH * 4);
  P.h0f   = (unsigned*)take((size_t)2 * FRAGN * 4);
  P.h1f   = (unsigned*)take((size_t)2 * FRAGN * 4);
  P.tvf   = (unsigned*)take((size_t)FRAGN * 4);

  hipMemsetAsync(d_ws, 0, 4096, stream);
  rnn_kernel<<<dim3(NWG), dim3(NTHR), 0, stream>>>(P);
}

// Round 9
// 15599.985 us; speedup vs baseline: 3.6647x; 1.0253x over previous
//
#include <hip/hip_runtime.h>
#include <hip/hip_bf16.h>

typedef __attribute__((ext_vector_type(8))) short bf16x8;
typedef __attribute__((ext_vector_type(4))) float f32x4;
typedef unsigned long long ull;

#define NB 512      // batch
#define NT 128      // timesteps
#define NC 66       // input channels
#define NH 512      // hidden
#define NW 10       // window
#define CP 96       // padded C (3 k-stages of 32)
#define BM 32       // batch tile
#define BJ 64       // j (h-dim) tile
#define NWG 256
#define NTHR 256
#define G3 1536     // 3*NH
#define NKS_H 16    // NH/32 k-stages
#define NKS_X 3     // CP/32 k-stages
#define FRAGN (NB * NH)   // u32 elems per frag buffer (1MB)

struct Params {
  const float *x, *Wih0, *Whh0, *bih0, *bhh0, *Wih1, *Whh1, *bih1, *bhh1, *tw, *tb, *sw, *sb;
  float *out;
  unsigned *barL, *barG;             // one-time global init barrier
  unsigned *cbar;                    // per-cluster (16x) phase barrier counters, 64B stride
  __hip_bfloat16 *Wih0h, *Wih0l;     // layer0 input weights, swizzled split, nks=3
  __hip_bfloat16 *Wch, *Wcl;         // composed Wc = Wih0 @ sw, swizzled split, nks=16
  __hip_bfloat16 *Whh0H, *Whh0L;     // swizzled split, nks=16
  __hip_bfloat16 *Wih1H, *Wih1L;
  __hip_bfloat16 *Whh1H, *Whh1L;
  float *cb;                         // cb = Wih0 @ sb  [G3]
  float *tvec;
  unsigned *h0f, *h1f, *tvf;         // packed split-bf16 A-fragment buffers
};

__device__ __forceinline__ float sigmoidf_(float x) { return 1.f / (1.f + __expf(-x)); }
__device__ __forceinline__ float tanhf_(float x) {
  float e = __expf(2.f * x);
  return (e - 1.f) / (e + 1.f);
}
__device__ __forceinline__ void split2(float v, __hip_bfloat16& h, __hip_bfloat16& l) {
  h = __float2bfloat16(v);
  l = __float2bfloat16(v - __bfloat162float(h));
}
__device__ __forceinline__ unsigned short bfbits(__hip_bfloat16 h) { return *(unsigned short*)&h; }
__device__ __forceinline__ void splitpack4(float4 v, ushort4& ph, ushort4& pl) {
  __hip_bfloat16 h, l;
  split2(v.x, h, l); ph.x = bfbits(h); pl.x = bfbits(l);
  split2(v.y, h, l); ph.y = bfbits(h); pl.y = bfbits(l);
  split2(v.z, h, l); ph.z = bfbits(h); pl.z = bfbits(l);
  split2(v.w, h, l); ph.w = bfbits(h); pl.w = bfbits(l);
}
// packed split-bf16: lo16 = hi-part, hi16 = lo-part
__device__ __forceinline__ unsigned packbf(float v) {
  __hip_bfloat16 h, l; split2(v, h, l);
  return (unsigned)bfbits(h) | ((unsigned)bfbits(l) << 16);
}
__device__ __forceinline__ unsigned short f2bfb(float v) {
  __hip_bfloat16 h = __float2bfloat16(v);
  return bfbits(h);
}
__device__ __forceinline__ float bfb2f(unsigned short u) {
  __hip_bfloat16 h = *(__hip_bfloat16*)&u;
  return __bfloat162float(h);
}

// async global->LDS, 16B/lane; LDS dest = wave-uniform base + lane*16
__device__ __forceinline__ void gld_lds16(const void* g, void* l) {
  __builtin_amdgcn_global_load_lds(
      (const __attribute__((address_space(1))) unsigned*)g,
      (__attribute__((address_space(3))) unsigned*)l, 16, 0, 0);
}

// One-time global barrier after init: RELEASE -> L2 writeback so plain-stored
// init data (weights) is chip-visible. Acquire fence on exit (L2 inv) so the
// cached-read phase starts clean. Poll: barG reaches 8.
__device__ __forceinline__ void gbar_init(unsigned* barL, unsigned* barG, int tid, int grp) {
  asm volatile("s_waitcnt vmcnt(0)" ::: "memory");
  __syncthreads();
  if (tid == 0) {
    unsigned old = __hip_atomic_fetch_add(&barL[grp * 32], 1u, __ATOMIC_RELEASE,
                                          __HIP_MEMORY_SCOPE_AGENT);
    if (old == 31u)
      __hip_atomic_fetch_add(barG, 1u, __ATOMIC_RELAXED, __HIP_MEMORY_SCOPE_AGENT);
    while (__hip_atomic_load(barG, __ATOMIC_RELAXED, __HIP_MEMORY_SCOPE_AGENT) < 8u)
      __builtin_amdgcn_s_sleep(2);
    __builtin_amdgcn_fence(__ATOMIC_ACQUIRE, "agent");   // L2 inv
  }
  __syncthreads();
  asm volatile("" ::: "memory");
}

// 16-WG cluster barrier (logical IDs only). Producers push cross-WG data with
// agent-scope (L3-direct) stores, drained by vmcnt(0) before arrival. On exit,
// tid0 executes an agent-acquire fence (buffer_inv: flash-invalidates this
// XCD's clean L2 lines) so subsequent PLAIN CACHED reads observe L3-fresh
// data. Nothing cross-WG is ever dirty-cached -> invalidation is sufficient.
__device__ __forceinline__ void xbar(unsigned* cnt, unsigned& ph, int tid) {
  asm volatile("s_waitcnt vmcnt(0)" ::: "memory");
  __syncthreads();
  ++ph;
  if (tid == 0) {
    __hip_atomic_fetch_add(cnt, 1u, __ATOMIC_RELAXED, __HIP_MEMORY_SCOPE_AGENT);
    while (__hip_atomic_load(cnt, __ATOMIC_RELAXED, __HIP_MEMORY_SCOPE_AGENT) < ph * 16u)
      __builtin_amdgcn_s_sleep(1);
    __builtin_amdgcn_fence(__ATOMIC_ACQUIRE, "agent");   // L2 inv
  }
  __syncthreads();
  asm volatile("" ::: "memory");
}

__device__ __forceinline__ void zacc(f32x4 acc[2][4]) {
#pragma unroll
  for (int i = 0; i < 2; ++i)
#pragma unroll
    for (int g = 0; g < 4; ++g) {
      acc[i][g][0] = 0.f; acc[i][g][1] = 0.f; acc[i][g][2] = 0.f; acc[i][g][3] = 0.f;
    }
}

// Bulk A-tile loader: 64KB contiguous from the frag buffer into LDS via fully
// async CACHED global_load_lds (16 x 1KB/wave in flight, zero data VGPRs, one
// drain). Coherent because xbar's acquire fence invalidated stale L2 lines;
// same-XCD cluster partners share the L2 fills (dedups redundancy).
__device__ __forceinline__ void bulk_a(unsigned* __restrict__ alds,
                                       const unsigned* __restrict__ frag,
                                       int bb0, int tid) {
  const int wv = tid >> 6, ln = tid & 63;
  const float4* g4 = (const float4*)(frag + (size_t)bb0 * 8192);
  float4* d4 = (float4*)alds;
#pragma unroll
  for (int i = 0; i < 16; ++i)
    gld_lds16(g4 + i * 256 + wv * 64 + ln, d4 + i * 256 + wv * 64);
  asm volatile("s_waitcnt vmcnt(0)" ::: "memory");
}

// (BM x 3*BJ) gate tile, nks=16: A from LDS frag tile; B staged via ASYNC
// global_load_lds into a double-buffered LDS slot (counted vmcnt, zero data
// VGPRs -> deep in-flight pipeline). Two s_barriers/stage bound wave skew so
// slot reuse cannot race. Math order identical to prior rounds.
template <int G2>
__device__ __forceinline__ void gemm_lds(
    f32x4 acc[2][4],
    const __hip_bfloat16* __restrict__ WH, const __hip_bfloat16* __restrict__ WL,
    const unsigned* __restrict__ aT, unsigned* __restrict__ Bst, int j0, int tid)
{
  const int wv = tid >> 6, lane = tid & 63;
  const int ms = wv & 1, jh = wv >> 1;

  const __hip_bfloat16* wsrc[12];
#pragma unroll
  for (int c = 0; c < 3; ++c)
#pragma unroll
    for (int jl = 0; jl < 2; ++jl) {
      const int jb = c * 32 + (j0 >> 4) + jh * 2 + jl;
      const unsigned bo = (unsigned)((jb * NKS_H) * 64 + lane) * 8u;
      wsrc[(c * 2 + jl) * 2 + 0] = WH + bo;
      wsrc[(c * 2 + jl) * 2 + 1] = WL + bo;
    }
  unsigned* const bb = Bst + jh * 6144;            // [jh][slot2][chunk12][256 u32]
  const unsigned* ab = aT + ms * 8192;
  const unsigned i0 = ((unsigned)(lane * 8)) ^ ((unsigned)(lane & 7) << 2);
  const int lofs = lane * 4;

  auto issueB = [&](int st) {
    unsigned* sb = bb + (st & 1) * 3072;
#pragma unroll
    for (int k = 0; k < 12; ++k)
      gld_lds16(wsrc[k] + (size_t)st * 512, sb + k * 256);
  };
  auto readA = [&](bf16x8& ah, bf16x8& al, int st) {
    const unsigned* ap = ab + st * 512;
    const uint4 ua = *(const uint4*)(ap + i0);          // elems e0..3
    const uint4 ub = *(const uint4*)(ap + (i0 ^ 4u));   // elems e4..7
    uint4 uh, ul;
    uh.x = (ua.x & 0xffffu) | (ua.y << 16);  ul.x = (ua.x >> 16) | (ua.y & 0xffff0000u);
    uh.y = (ua.z & 0xffffu) | (ua.w << 16);  ul.y = (ua.z >> 16) | (ua.w & 0xffff0000u);
    uh.z = (ub.x & 0xffffu) | (ub.y << 16);  ul.z = (ub.x >> 16) | (ub.y & 0xffff0000u);
    uh.w = (ub.z & 0xffffu) | (ub.w << 16);  ul.w = (ub.z >> 16) | (ub.w & 0xffff0000u);
    ah = *(const bf16x8*)&uh;
    al = *(const bf16x8*)&ul;
  };

  issueB(0); issueB(1);
  for (int st = 0; st < NKS_H; ++st) {
    unsigned* sb = bb + (st & 1) * 3072;
    if (st < NKS_H - 1) { asm volatile("s_waitcnt vmcnt(12)" ::: "memory"); }
    else                { asm volatile("s_waitcnt vmcnt(0)"  ::: "memory"); }
    __builtin_amdgcn_sched_barrier(0);
    __builtin_amdgcn_s_barrier();                   // all waves' st-loads landed
    bf16x8 ah, al;
    readA(ah, al, st);
    bf16x8 vbh[6], vbl[6];
#pragma unroll
    for (int f = 0; f < 6; ++f) {
      vbh[f] = *(const bf16x8*)(sb + (f * 2 + 0) * 256 + lofs);
      vbl[f] = *(const bf16x8*)(sb + (f * 2 + 1) * 256 + lofs);
    }
    asm volatile("s_waitcnt lgkmcnt(0)" ::: "memory");
    __builtin_amdgcn_sched_barrier(0);
    __builtin_amdgcn_s_barrier();                   // all waves done reading slot
    if (st + 2 < NKS_H) issueB(st + 2);
#pragma unroll
    for (int jl = 0; jl < 2; ++jl)
#pragma unroll
      for (int c = 0; c < 3; ++c) {
        const int f = c * 2 + jl;
        const int g = (c == 2) ? G2 : c;
        acc[jl][g] = __builtin_amdgcn_mfma_f32_16x16x32_bf16(ah, vbh[f], acc[jl][g], 0, 0, 0);
        acc[jl][g] = __builtin_amdgcn_mfma_f32_16x16x32_bf16(al, vbh[f], acc[jl][g], 0, 0, 0);
        acc[jl][g] = __builtin_amdgcn_mfma_f32_16x16x32_bf16(ah, vbl[f], acc[jl][g], 0, 0, 0);
      }
  }
}

// x-input gate tile (nks=3): x is an immutable input -> plain cached loads.
template <int G2>
__device__ __forceinline__ void gemm_x(
    f32x4 acc[2][4],
    const __hip_bfloat16* __restrict__ WH, const __hip_bfloat16* __restrict__ WL,
    const float* __restrict__ X, int tstep, int b0, int j0, int tid)
{
  const int wv = tid >> 6, lane = tid & 63, quad = lane >> 4, l15 = lane & 15;
  const int ms = wv & 1, jh = wv >> 1;
  const int arow = b0 + ms * 16 + l15;

  unsigned boff[6];
#pragma unroll
  for (int c = 0; c < 3; ++c)
#pragma unroll
    for (int jl = 0; jl < 2; ++jl) {
      const int jb = c * 32 + (j0 >> 4) + jh * 2 + jl;
      boff[c * 2 + jl] = (unsigned)((jb * NKS_X) * 64 + lane) * 8u;
    }
  const float* arp = X + ((size_t)arow * NT + tstep) * NC;

  float a[3][8];
#pragma unroll
  for (int st = 0; st < 3; ++st) {
    const int k0 = st * 32 + (quad << 3);
#pragma unroll
    for (int e = 0; e < 8; ++e) a[st][e] = (k0 + e < NC) ? arp[k0 + e] : 0.f;
  }

  uint4 bh0[6], bl0[6], bh1[6], bl1[6];
  auto loadB = [&](uint4 (&bh)[6], uint4 (&bl)[6], int st) {
    const unsigned so = (unsigned)st * 512u;
#pragma unroll
    for (int f = 0; f < 6; ++f) {
      bh[f] = *(const uint4*)(WH + boff[f] + so);
      bl[f] = *(const uint4*)(WL + boff[f] + so);
    }
  };
  auto comp = [&](const uint4 (&bh)[6], const uint4 (&bl)[6], const float (&av)[8]) {
    float4 v0, v1;
    v0.x = av[0]; v0.y = av[1]; v0.z = av[2]; v0.w = av[3];
    v1.x = av[4]; v1.y = av[5]; v1.z = av[6]; v1.w = av[7];
    ushort4 ph0, pl0, ph1, pl1;
    splitpack4(v0, ph0, pl0);
    splitpack4(v1, ph1, pl1);
    bf16x8 ah, al;
    ((ushort4*)&ah)[0] = ph0; ((ushort4*)&ah)[1] = ph1;
    ((ushort4*)&al)[0] = pl0; ((ushort4*)&al)[1] = pl1;
#pragma unroll
    for (int jl = 0; jl < 2; ++jl)
#pragma unroll
      for (int c = 0; c < 3; ++c) {
        const int f = c * 2 + jl;
        const int g = (c == 2) ? G2 : c;
        const bf16x8 vbh = *(const bf16x8*)&bh[f];
        const bf16x8 vbl = *(const bf16x8*)&bl[f];
        acc[jl][g] = __builtin_amdgcn_mfma_f32_16x16x32_bf16(ah, vbh, acc[jl][g], 0, 0, 0);
        acc[jl][g] = __builtin_amdgcn_mfma_f32_16x16x32_bf16(al, vbh, acc[jl][g], 0, 0, 0);
        acc[jl][g] = __builtin_amdgcn_mfma_f32_16x16x32_bf16(ah, vbl, acc[jl][g], 0, 0, 0);
      }
  };

  loadB(bh0, bl0, 0); loadB(bh1, bl1, 1);
  comp(bh0, bl0, a[0]);
  loadB(bh0, bl0, 2);
  comp(bh1, bl1, a[1]);
  comp(bh0, bl0, a[2]);
}

// GRU elementwise. h-hold carried in REGISTERS. Window (if any) in LDS ring.
// Cross-WG frag: staged in LDS then contiguous agent-scope store sweep.
__device__ __forceinline__ void ew_gru(
    f32x4 acc[2][4],
    const float* __restrict__ bi, const float* __restrict__ bh,
    float (&hreg)[2][4],
    unsigned* __restrict__ hfrag,
    int b0, int j0, int tid, ushort* winl, int slot,
    unsigned* __restrict__ stg)
{
  const int wv = tid >> 6, lane = tid & 63, quad = lane >> 4, l15 = lane & 15;
  const int ms = wv & 1, jh = wv >> 1;
  const int bb0 = b0 >> 4, jcb = j0 >> 5;
  __syncthreads();   // staging buffer may still be read by lagging gemm threads
#pragma unroll
  for (int jlf = 0; jlf < 2; ++jlf) {
    const int j = j0 + jh * 32 + jlf * 16 + l15;
    const float br = bi[j] + bh[j];
    const float bz = bi[NH + j] + bh[NH + j];
    const float bni = bi[2 * NH + j];
    const float bnh = bh[2 * NH + j];
#pragma unroll
    for (int rg = 0; rg < 4; ++rg) {
      const float r = sigmoidf_(acc[jlf][0][rg] + br);
      const float z = sigmoidf_(acc[jlf][1][rg] + bz);
      const float n = tanhf_(acc[jlf][2][rg] + bni + r * (acc[jlf][3][rg] + bnh));
      const float h = hreg[jlf][rg];
      const float hn = (1.f - z) * n + z * h;
      hreg[jlf][rg] = hn;
      const int lanep = (quad * 4 + rg) | ((jlf * 2 + (l15 >> 3)) << 4);
      const int s = (lanep * 8 + (l15 & 7)) ^ ((lanep & 7) << 2);
      stg[ms * 1024 + jh * 512 + s] = packbf(hn);
      if (winl) winl[slot * 2048 + (jlf * 4 + rg) * 256 + tid] = f2bfb(hn);
    }
  }
  __syncthreads();
#pragma unroll
  for (int i = 0; i < 4; ++i) {
    const int q = i * 256 + tid;
    const int chunk = q >> 9, rem = q & 511;
    ull* gb = (ull*)hfrag + ((size_t)(bb0 + chunk) * 16 + jcb) * 256;
    __hip_atomic_store(gb + rem, ((const ull*)stg)[q],
                       __ATOMIC_RELAXED, __HIP_MEMORY_SCOPE_AGENT);
  }
}

// decoder layer-1 EW: h1 hold in registers; window ring in LDS; h1f + tvf
// frags via LDS-staged agent sweep; tvec fp32 via agent stores.
__device__ __forceinline__ void ew_dec1(
    f32x4 acc[2][4], const Params& P, float (&hreg)[2][4],
    int b0, int j0, int tid, int s, unsigned* __restrict__ stg, ushort* winl)
{
  const int wv = tid >> 6, lane = tid & 63, quad = lane >> 4, l15 = lane & 15;
  const int ms = wv & 1, jh = wv >> 1;
  const int bb0 = b0 >> 4, jcb = j0 >> 5;
  const int slot = s % NW;
  float twv[NW];
#pragma unroll
  for (int k = 0; k < NW; ++k) {
    int idx = k - slot - 1; if (idx < 0) idx += NW;
    twv[k] = P.tw[idx];
  }
  const float tw9 = P.tw[NW - 1];
  const float tb0 = P.tb[0];
  __syncthreads();
#pragma unroll
  for (int jlf = 0; jlf < 2; ++jlf) {
    const int j = j0 + jh * 32 + jlf * 16 + l15;
    const float br = P.bih1[j] + P.bhh1[j];
    const float bz = P.bih1[NH + j] + P.bhh1[NH + j];
    const float bni = P.bih1[2 * NH + j];
    const float bnh = P.bhh1[2 * NH + j];
#pragma unroll
    for (int rg = 0; rg < 4; ++rg) {
      const int b = b0 + ms * 16 + quad * 4 + rg;
      const float r = sigmoidf_(acc[jlf][0][rg] + br);
      const float z = sigmoidf_(acc[jlf][1][rg] + bz);
      const float n = tanhf_(acc[jlf][2][rg] + bni + r * (acc[jlf][3][rg] + bnh));
      const float h = hreg[jlf][rg];
      const float hn = (1.f - z) * n + z * h;
      hreg[jlf][rg] = hn;
      const int widx = (jlf * 4 + rg) * 256 + tid;
      winl[slot * 2048 + widx] = f2bfb(hn);
      float ts = tb0 + hn * tw9;
#pragma unroll
      for (int k = 0; k < NW; ++k) {
        if (k == slot) continue;
        ts += bfb2f(winl[k * 2048 + widx]) * twv[k];
      }
      __hip_atomic_store(&P.tvec[(size_t)b * NH + j], ts,
                         __ATOMIC_RELAXED, __HIP_MEMORY_SCOPE_AGENT);
      const int lanep = (quad * 4 + rg) | ((jlf * 2 + (l15 >> 3)) << 4);
      const int sw = (lanep * 8 + (l15 & 7)) ^ ((lanep & 7) << 2);
      stg[ms * 1024 + jh * 512 + sw] = packbf(hn);
      stg[2048 + ms * 1024 + jh * 512 + sw] = packbf(ts);
    }
  }
  __syncthreads();
#pragma unroll
  for (int i = 0; i < 8; ++i) {
    const int q2 = i * 256 + tid;
    const int buf = q2 >> 10, q = q2 & 1023;
    const int chunk = q >> 9, rem = q & 511;
    unsigned* base = buf ? P.tvf : (P.h1f + FRAGN);
    ull* gb = (ull*)base + ((size_t)(bb0 + chunk) * 16 + jcb) * 256;
    __hip_atomic_store(gb + rem, ((const ull*)stg)[q2],
                       __ATOMIC_RELAXED, __HIP_MEMORY_SCOPE_AGENT);
  }
}

__global__ __launch_bounds__(NTHR) void rnn_kernel(Params P) {
  __shared__ __align__(16) unsigned aT[16384];    // 64KB A-tile (+ ew staging)
  __shared__ __align__(16) unsigned Bst[12288];   // 48KB async B staging
  __shared__ __align__(16) ushort wtl[20480];     // 40KB: winl (L1) / tl (L0) overlay
  float* tl = (float*)wtl;
  ushort* winlb = wtl;
  const int tid = threadIdx.x;
  const int wg = blockIdx.x;
  const int grp = wg & 7;
  const size_t gid = (size_t)wg * NTHR + tid;
  const size_t GT = (size_t)NWG * NTHR;
  const int wv = tid >> 6, lane = tid & 63, l15 = lane & 15;
  const int jh = wv >> 1;

  // ---- logical roles ----
  const bool isL1 = wg >= 128;
  const int tile = wg & 127;
  const int b0 = (tile >> 3) * BM;
  const int j0 = (tile & 7) * BJ;
  const int bb0 = b0 >> 4;
  const int jidx = tile & 7;
  const int cluster = tile >> 3;                 // 16 independent b-block clusters
  unsigned* ccnt = P.cbar + (size_t)cluster * 16;

  // ---- init: build swizzled split-bf16 weights ----
  for (size_t f = gid; f < (size_t)G3 * CP / 8; f += GT) {
    const int ln = (int)(f & 63), blk = (int)(f >> 6);
    const int ks = blk % NKS_X, jb = blk / NKS_X;
    const int r = jb * 16 + (ln & 15);
    const int k0 = ks * 32 + ((ln >> 4) << 3);
#pragma unroll
    for (int e = 0; e < 8; ++e) {
      const int k = k0 + e;
      split2(k < NC ? P.Wih0[(size_t)r * NC + k] : 0.f,
             P.Wih0h[f * 8 + e], P.Wih0l[f * 8 + e]);
    }
  }
  {
    const float* srcs[3] = { P.Whh0, P.Wih1, P.Whh1 };
    __hip_bfloat16* dhs[3] = { P.Whh0H, P.Wih1H, P.Whh1H };
    __hip_bfloat16* dls[3] = { P.Whh0L, P.Wih1L, P.Whh1L };
#pragma unroll
    for (int m = 0; m < 3; ++m) {
      const float* __restrict__ W = srcs[m];
      __hip_bfloat16* __restrict__ DH = dhs[m];
      __hip_bfloat16* __restrict__ DL = dls[m];
      for (size_t f = gid; f < (size_t)G3 * NH / 8; f += GT) {
        const int ln = (int)(f & 63), blk = (int)(f >> 6);
        const int ks = blk & 15, jb = blk >> 4;
        const int r = jb * 16 + (ln & 15);
        const int k0 = ks * 32 + ((ln >> 4) << 3);
        const float* src = W + (size_t)r * NH + k0;
        ushort4 h0v, l0v, h1v, l1v;
        splitpack4(*(const float4*)(src), h0v, l0v);
        splitpack4(*(const float4*)(src + 4), h1v, l1v);
        *(ushort4*)(DH + f * 8)     = h0v;
        *(ushort4*)(DH + f * 8 + 4) = h1v;
        *(ushort4*)(DL + f * 8)     = l0v;
        *(ushort4*)(DL + f * 8 + 4) = l1v;
      }
    }
  }
  for (size_t f = gid; f < (size_t)G3 * NH / 8; f += GT) {
    const int ln = (int)(f & 63), blk = (int)(f >> 6);
    const int ks = blk & 15, jb = blk >> 4;
    const int r = jb * 16 + (ln & 15);
    const int k0 = ks * 32 + ((ln >> 4) << 3);
    float s[8] = {0.f, 0.f, 0.f, 0.f, 0.f, 0.f, 0.f, 0.f};
    for (int c = 0; c < NC; ++c) {
      const float a = P.Wih0[(size_t)r * NC + c];
      const float4 w0 = *(const float4*)(P.sw + (size_t)c * NH + k0);
      const float4 w1 = *(const float4*)(P.sw + (size_t)c * NH + k0 + 4);
      s[0] += a * w0.x; s[1] += a * w0.y; s[2] += a * w0.z; s[3] += a * w0.w;
      s[4] += a * w1.x; s[5] += a * w1.y; s[6] += a * w1.z; s[7] += a * w1.w;
    }
#pragma unroll
    for (int e = 0; e < 8; ++e) split2(s[e], P.Wch[f * 8 + e], P.Wcl[f * 8 + e]);
  }
  for (size_t i = gid; i < (size_t)G3; i += GT) {
    float a = 0.f;
    for (int c = 0; c < NC; ++c) a += P.Wih0[i * NC + c] * P.sb[c];
    P.cb[i] = a;
  }
  // ---- role-based zeroing via agent stores ----
  {
    unsigned* z = (!isL1 ? P.h0f : (P.h1f + FRAGN)) + (size_t)bb0 * 8192 + (size_t)jidx * 2048;
    for (int i = tid; i < 2048; i += NTHR)
      __hip_atomic_store(z + i, 0u, __ATOMIC_RELAXED, __HIP_MEMORY_SCOPE_AGENT);
  }
  gbar_init(P.barL, P.barG, tid, grp);   // one-time global release barrier

  unsigned ph = 0;
  float G[2][3][4];
  float hreg[2][4] = {{0.f, 0.f, 0.f, 0.f}, {0.f, 0.f, 0.f, 0.f}};
  f32x4 whh[2][4];   // L0 decoder pipeline: saved Whh0 @ h0_s (entries 0,1,3 live)

  // ---- encoder: pipelined L0/L1, one cluster barrier per iteration ----
  for (int t = 0; t <= NT; ++t) {
    const int cur = t & 1;
    f32x4 acc[2][4];
    if (!isL1) {
      if (t < NT) {
        zacc(acc);
        bulk_a(aT, P.h0f + (size_t)cur * FRAGN, bb0, tid);
        gemm_x<2>(acc, P.Wih0h, P.Wih0l, P.x, t, b0, j0, tid);
        __syncthreads();
        gemm_lds<3>(acc, P.Whh0H, P.Whh0L, aT, Bst, j0, tid);
        ew_gru(acc, P.bih0, P.bhh0, hreg, P.h0f + (size_t)(cur ^ 1) * FRAGN,
               b0, j0, tid, nullptr, 0, aT);
      } else {
        // G_0 = x[:,127,:] @ Wih0^T ; and prime the decoder's whh pipeline
        // with Whh0 @ h0_T (h0f buf0 holds h0_T here: cur = 0).
        zacc(acc);
        bulk_a(aT, P.h0f + (size_t)cur * FRAGN, bb0, tid);
        gemm_x<2>(acc, P.Wih0h, P.Wih0l, P.x, NT - 1, b0, j0, tid);
#pragma unroll
        for (int jlf = 0; jlf < 2; ++jlf)
#pragma unroll
          for (int c = 0; c < 3; ++c)
#pragma unroll
            for (int rg = 0; rg < 4; ++rg) G[jlf][c][rg] = acc[jlf][c][rg];
        __syncthreads();
        zacc(whh);
        gemm_lds<3>(whh, P.Whh0H, P.Whh0L, aT, Bst, j0, tid);
      }
    } else {
      if (t >= 1) {
        zacc(acc);
        bulk_a(aT, P.h0f + (size_t)cur * FRAGN, bb0, tid);
        __syncthreads();
        gemm_lds<2>(acc, P.Wih1H, P.Wih1L, aT, Bst, j0, tid);
        __syncthreads();
        bulk_a(aT, P.h1f + (size_t)cur * FRAGN, bb0, tid);
        __syncthreads();
        gemm_lds<3>(acc, P.Whh1H, P.Whh1L, aT, Bst, j0, tid);
        ew_gru(acc, P.bih1, P.bhh1, hreg, P.h1f + (size_t)(cur ^ 1) * FRAGN,
               b0, j0, tid, (t >= 119) ? winlb : nullptr, t - 119, aT);
      }
    }
    xbar(ccnt, ph, tid);
  }

  int d0 = 0;

  float cbr[2][3];
  float Freg[2];
  const int frow = wg * 4;   // L0 frame rows
  if (!isL1) {
#pragma unroll
    for (int jlf = 0; jlf < 2; ++jlf)
#pragma unroll
      for (int c = 0; c < 3; ++c)
        cbr[jlf][c] = P.cb[c * NH + j0 + jh * 32 + jlf * 16 + l15];
#pragma unroll
    for (int v = 0; v < 2; ++v) {
      const int t2 = tid + v * NTHR;
      if (t2 < 4 * NC) {
        const int bl = t2 / NC, c = t2 - bl * NC, b = frow + bl;
        Freg[v] = P.x[((size_t)b * NT + (NT - 1)) * NC + c];
      }
    }
  }

  auto frame_out = [&](int sout) {
    const float* tvb = P.tvec + (size_t)frow * NH;
    *(float4*)&tl[tid * 8] = *(const float4*)(tvb + tid * 8);       // cached (post-inv)
    *(float4*)&tl[tid * 8 + 4] = *(const float4*)(tvb + tid * 8 + 4);
    __syncthreads();
#pragma unroll
    for (int v = 0; v < 2; ++v) {
      const int t2 = tid + v * NTHR;
      if (t2 < 4 * NC) {
        const int bl = t2 / NC, c = t2 - bl * NC, b = frow + bl;
        float f = Freg[v] + P.sb[c];
        const float4* swr = (const float4*)(P.sw + (size_t)c * NH);
        const float4* tr = (const float4*)(tl + bl * NH);
#pragma unroll 8
        for (int h4 = 0; h4 < NH / 4; ++h4) {
          float4 tv = tr[h4], wv4 = swr[h4];
          f += tv.x * wv4.x + tv.y * wv4.y + tv.z * wv4.z + tv.w * wv4.w;
        }
        Freg[v] = f;
        __builtin_nontemporal_store(f, &P.out[((size_t)b * NT + sout) * NC + c]);
      }
    }
    __syncthreads();
  };

  // ---- decoder: rebalanced, 1 gemm/WG per phase, 2 cluster barriers/step ----
  // Phase A: L0: Wc-gemm + G-update + saved-whh add + ew  | L1: Whh1-gemm
  // Phase B: L0: Whh0-gemm on fresh h0f -> whh (for s+1)  | L1: Wih1-gemm + ew_dec1
  for (int s = 0; s < NT; ++s) {
    f32x4 acc[2][4];
    if (!isL1) {
      zacc(acc);
      if (s >= 1) {
        frame_out(s - 1);
        bulk_a(aT, P.tvf, bb0, tid);
        __syncthreads();
        gemm_lds<2>(acc, P.Wch, P.Wcl, aT, Bst, j0, tid);
      }
#pragma unroll
      for (int jlf = 0; jlf < 2; ++jlf) {
#pragma unroll
        for (int c = 0; c < 3; ++c)
#pragma unroll
          for (int rg = 0; rg < 4; ++rg) {
            float g = G[jlf][c][rg] + acc[jlf][c][rg] + (s >= 1 ? cbr[jlf][c] : 0.f);
            G[jlf][c][rg] = g;
            acc[jlf][c][rg] = g;
          }
#pragma unroll
        for (int rg = 0; rg < 4; ++rg) {
          acc[jlf][0][rg] += whh[jlf][0][rg];
          acc[jlf][1][rg] += whh[jlf][1][rg];
          acc[jlf][3][rg]  = whh[jlf][3][rg];
        }
      }
      ew_gru(acc, P.bih0, P.bhh0, hreg, P.h0f + (size_t)(d0 ^ 1) * FRAGN,
             b0, j0, tid, nullptr, 0, aT);
    } else {
      zacc(acc);
      bulk_a(aT, P.h1f + (size_t)FRAGN, bb0, tid);
      __syncthreads();
      gemm_lds<3>(acc, P.Whh1H, P.Whh1L, aT, Bst, j0, tid);
      __syncthreads();
    }
    xbar(ccnt, ph, tid);
    if (!isL1) {
      if (s < NT - 1) {
        bulk_a(aT, P.h0f + (size_t)(d0 ^ 1) * FRAGN, bb0, tid);
        __syncthreads();
        zacc(whh);
        gemm_lds<3>(whh, P.Whh0H, P.Whh0L, aT, Bst, j0, tid);
      }
    } else {
      bulk_a(aT, P.h0f + (size_t)(d0 ^ 1) * FRAGN, bb0, tid);
      __syncthreads();
      gemm_lds<2>(acc, P.Wih1H, P.Wih1L, aT, Bst, j0, tid);
      ew_dec1(acc, P, hreg, b0, j0, tid, s, aT, winlb);
    }
    xbar(ccnt, ph, tid);
    d0 ^= 1;
  }
  if (!isL1) frame_out(NT - 1);
}

extern "C" void kernel_launch(void* const* d_in, const int* in_sizes, int n_in,
                              void* d_out, int out_size, void* d_ws, size_t ws_size,
                              hipStream_t stream) {
  (void)in_sizes; (void)n_in; (void)out_size; (void)ws_size;
  Params P;
  P.x    = (const float*)d_in[0];
  P.Wih0 = (const float*)d_in[1];
  P.Whh0 = (const float*)d_in[2];
  P.bih0 = (const float*)d_in[3];
  P.bhh0 = (const float*)d_in[4];
  P.Wih1 = (const float*)d_in[5];
  P.Whh1 = (const float*)d_in[6];
  P.bih1 = (const float*)d_in[7];
  P.bhh1 = (const float*)d_in[8];
  P.tw   = (const float*)d_in[9];
  P.tb   = (const float*)d_in[10];
  P.sw   = (const float*)d_in[11];
  P.sb   = (const float*)d_in[12];
  P.out  = (float*)d_out;

  char* w = (char*)d_ws;
  size_t used = 0;
  auto take = [&](size_t bytes) {
    char* p = w + used;
    used += (bytes + 255) & ~(size_t)255;
    return p;
  };
  unsigned* bar = (unsigned*)take(4096);
  P.barL  = bar;            // 8 groups * 32-stride u32 = 1024B
  P.barG  = bar + 256;
  P.cbar  = bar + 320;      // 16 clusters * 16 u32 (64B stride)
  P.Wih0h = (__hip_bfloat16*)take((size_t)G3 * CP * 2);
  P.Wih0l = (__hip_bfloat16*)take((size_t)G3 * CP * 2);
  P.Wch   = (__hip_bfloat16*)take((size_t)G3 * NH * 2);
  P.Wcl   = (__hip_bfloat16*)take((size_t)G3 * NH * 2);
  P.Whh0H = (__hip_bfloat16*)take((size_t)G3 * NH * 2);
  P.Whh0L = (__hip_bfloat16*)take((size_t)G3 * NH * 2);
  P.Wih1H = (__hip_bfloat16*)take((size_t)G3 * NH * 2);
  P.Wih1L = (__hip_bfloat16*)take((size_t)G3 * NH * 2);
  P.Whh1H = (__hip_bfloat16*)take((size_t)G3 * NH * 2);
  P.Whh1L = (__hip_bfloat16*)take((size_t)G3 * NH * 2);
  P.cb    = (float*)take((size_t)G3 * 4);
  P.tvec  = (float*)take((size_t)NB * NH * 4);
  P.h0f   = (unsigned*)take((size_t)2 * FRAGN * 4);
  P.h1f   = (unsigned*)take((size_t)2 * FRAGN * 4);
  P.tvf   = (unsigned*)take((size_t)FRAGN * 4);

  hipMemsetAsync(d_ws, 0, 4096, stream);
  rnn_kernel<<<dim3(NWG), dim3(NTHR), 0, stream>>>(P);
}